// Round 13
// baseline (182.279 us; speedup 1.0000x reference)
//
#include <hip/hip_runtime.h>
#include <math.h>

#define MGT 32
#define NCLS 80
#define TEPS 1e-9f
#define CEPS 1e-7f
#define CAPMAX 4096

// hoisted-precompute CIoU: awh=w1*h1, aatan=atan(w1/(h1+eps)) for box a (gt),
// bwh/batan likewise for box b (pred). Bit-identical to the reference op order.
__device__ __forceinline__ float ciou_pre(float ax1, float ay1, float ax2, float ay2,
                                          float awh, float aatan,
                                          float bx1, float by1, float bx2, float by2,
                                          float bwh, float batan) {
    float iw = fmaxf(fminf(ax2, bx2) - fmaxf(ax1, bx1), 0.f);
    float ih = fmaxf(fminf(ay2, by2) - fmaxf(ay1, by1), 0.f);
    float inter = iw * ih;
    float uni = awh + bwh - inter + CEPS;
    float iou = inter / uni;
    float cw = fmaxf(ax2, bx2) - fminf(ax1, bx1);
    float ch = fmaxf(ay2, by2) - fminf(ay1, by1);
    float c2 = cw * cw + ch * ch + CEPS;
    float dx = bx1 + bx2 - ax1 - ax2;
    float dy = by1 + by2 - ay1 - ay2;
    float rho2 = (dx * dx + dy * dy) * 0.25f;
    float dv = batan - aatan;
    float v = 0.405284734569351f * dv * dv;  // 4/pi^2
    float alpha = v / (v - iou + (1.f + CEPS));
    return iou - (rho2 / c2 + v * alpha);
}

__device__ __forceinline__ float sigm_fast(float x) {
    return __builtin_amdgcn_rcpf(1.f + __expf(-x));
}

// ---- kernel: sparse align -> compact per-(b,m) candidate lists; zero-inits ----
// key = bits(al)<<32 | ~n : exact (max-val, min-idx) order; only al>0 appended.
__global__ __launch_bounds__(256) void k_cand(const float* __restrict__ cls,
                                              const float* __restrict__ bdec,
                                              const float* __restrict__ tgt,
                                              const float* __restrict__ anc,
                                              unsigned long long* __restrict__ cand,
                                              unsigned* __restrict__ cnt,
                                              unsigned* __restrict__ selmask,
                                              unsigned* __restrict__ pos_al,
                                              unsigned* __restrict__ pos_ov,
                                              int Nv, int cap) {
    __shared__ float sx1[MGT], sy1[MGT], sx2[MGT], sy2[MGT];
    __shared__ float swh[MGT], satan[MGT];
    __shared__ int slab[MGT], svld[MGT];
    int b = blockIdx.y, tid = threadIdx.x;
    if (tid < MGT) {
        const float* t = tgt + ((size_t)b * MGT + tid) * 5;
        float lf = t[0];
        float x1 = t[1], y1 = t[2], x2 = t[3], y2 = t[4];
        sx1[tid] = x1; sy1[tid] = y1; sx2[tid] = x2; sy2[tid] = y2;
        float gw = x2 - x1, gh = y2 - y1;
        swh[tid] = gw * gh;
        satan[tid] = atanf(gw / (gh + CEPS));
        float area = fmaxf(gw, 0.f) * fmaxf(gh, 0.f);
        int lab = (int)lf;
        svld[tid] = (lab >= 0 && area > 0.f) ? 1 : 0;
        slab[tid] = lab < 0 ? 0 : lab;
        if (blockIdx.x == 0) {  // zero pos maxes once per batch-row
            pos_al[b * MGT + tid] = 0u;
            pos_ov[b * MGT + tid] = 0u;
        }
    }
    __syncthreads();
    int n = blockIdx.x * 256 + tid;
    if (n >= Nv) return;
    size_t bn = (size_t)b * Nv + n;
    selmask[bn] = 0u;  // stream-ordered before k_topk2 ORs
    float4 p = reinterpret_cast<const float4*>(bdec)[bn];
    float2 a = reinterpret_cast<const float2*>(anc)[n];
    const float* crow = cls + bn * NCLS;
    float pw = p.z - p.x, ph = p.w - p.y;
    float pwh = pw * ph;
    float patan = 0.f; bool have_patan = false;
    int lane = tid & 63;
    for (int m = 0; m < MGT; ++m) {
        float al = 0.f;
        if (svld[m]) {
            float mn = fminf(fminf(a.x - sx1[m], a.y - sy1[m]),
                             fminf(sx2[m] - a.x, sy2[m] - a.y));
            if (mn > TEPS) {  // sparse: ~2% of pairs reach CIoU
                if (!have_patan) { patan = atanf(pw / (ph + CEPS)); have_patan = true; }
                float ov = fmaxf(ciou_pre(sx1[m], sy1[m], sx2[m], sy2[m],
                                          swh[m], satan[m],
                                          p.x, p.y, p.z, p.w, pwh, patan), 0.f);
                if (ov > 0.f) {
                    float s = sigm_fast(crow[slab[m]]);
                    float o2 = ov * ov;
                    al = __builtin_sqrtf(s) * o2 * o2 * o2;  // s^0.5 * ov^6
                }
            }
        }
        // wave-aggregated append (order within list is irrelevant: set semantics)
        unsigned long long msk = __ballot(al > 0.f);
        if (msk) {
            int leader = __ffsll((long long)msk) - 1;
            unsigned base = 0;
            if (lane == leader)
                base = atomicAdd(&cnt[b * MGT + m], (unsigned)__popcll(msk));
            base = __shfl(base, leader, 64);
            if (al > 0.f) {
                unsigned rank = (unsigned)__popcll(msk & ((1ull << lane) - 1ull));
                unsigned idx = base + rank;
                if ((int)idx < cap) {
                    unsigned long long key =
                        (((unsigned long long)__float_as_uint(al)) << 32) |
                        (unsigned)(0xFFFFFFFFu - (unsigned)n);
                    cand[((size_t)b * MGT + m) * cap + idx] = key;
                }
            }
        }
    }
}

// ---- kernel: per-(b,m) top-10 from compact list -> selmask (register queue) ----
__global__ __launch_bounds__(256) void k_topk2(const unsigned long long* __restrict__ cand,
                                               const unsigned* __restrict__ cnt,
                                               unsigned* __restrict__ selmask,
                                               int Nv, int cap) {
    __shared__ unsigned long long warp_r[4];
    __shared__ unsigned long long winner_s;
    int bid = blockIdx.x;          // = b*MGT + m
    int b = bid / MGT, m = bid - b * MGT;
    int tid = threadIdx.x;
    int total = (int)cnt[bid];
    if (total > cap) total = cap;
    const unsigned long long* row = cand + (size_t)bid * cap;
    unsigned long long v[10];  // ascending; v[9] = max
#pragma unroll
    for (int i = 0; i < 10; ++i) v[i] = 0ull;
    for (int i = tid; i < total; i += 256) {
        unsigned long long key = row[i];
        if (key > v[0]) {  // sorted ascending insert
            unsigned long long cv = key; bool placed = false;
#pragma unroll
            for (int j = 0; j < 9; ++j) {
                if (!placed) {
                    if (cv > v[j + 1]) { v[j] = v[j + 1]; }
                    else { v[j] = cv; placed = true; }
                }
            }
            if (!placed) v[9] = cv;
        }
    }
    for (int r = 0; r < 10; ++r) {
        unsigned long long cand_k = v[9];
        unsigned long long w = cand_k;
#pragma unroll
        for (int s = 32; s > 0; s >>= 1) {
            unsigned long long o = __shfl_xor(w, s, 64);
            w = (o > w) ? o : w;
        }
        if ((tid & 63) == 0) warp_r[tid >> 6] = w;
        __syncthreads();
        if (tid == 0) {
            unsigned long long ww = warp_r[0];
            ww = (warp_r[1] > ww) ? warp_r[1] : ww;
            ww = (warp_r[2] > ww) ? warp_r[2] : ww;
            ww = (warp_r[3] > ww) ? warp_r[3] : ww;
            winner_s = ww;
            float wv = __uint_as_float((unsigned)(ww >> 32));
            if (wv > TEPS) {
                unsigned wi = 0xFFFFFFFFu - (unsigned)(ww & 0xFFFFFFFFull);
                atomicOr(&selmask[(size_t)b * Nv + wi], 1u << m);
            }
        }
        __syncthreads();
        unsigned long long win = winner_s;
        if (win == 0ull) break;  // no more positive candidates
        if (cand_k == win) {     // unique owner (idx embedded): pop max, shift up
#pragma unroll
            for (int j = 9; j > 0; --j) v[j] = v[j - 1];
            v[0] = 0ull;
        }
        __syncthreads();
    }
}

// ---- kernel: resolve multi-assignment (lazy bestm), per-anchor gt/align/ciou ----
__global__ __launch_bounds__(256) void k_resolve(const float* __restrict__ cls,
                                                 const float* __restrict__ bdec,
                                                 const float* __restrict__ tgt,
                                                 const float* __restrict__ anc,
                                                 const unsigned* __restrict__ selmask,
                                                 int* __restrict__ gtf,
                                                 float* __restrict__ amv,
                                                 float* __restrict__ crv,
                                                 unsigned* __restrict__ pos_al,
                                                 unsigned* __restrict__ pos_ov, int Nv) {
    __shared__ float sx1[MGT], sy1[MGT], sx2[MGT], sy2[MGT];
    __shared__ float swh[MGT], satan[MGT];
    __shared__ int slab[MGT], svld[MGT];
    int b = blockIdx.y, tid = threadIdx.x;
    if (tid < MGT) {
        const float* t = tgt + ((size_t)b * MGT + tid) * 5;
        float lf = t[0];
        float x1 = t[1], y1 = t[2], x2 = t[3], y2 = t[4];
        sx1[tid] = x1; sy1[tid] = y1; sx2[tid] = x2; sy2[tid] = y2;
        float gw = x2 - x1, gh = y2 - y1;
        swh[tid] = gw * gh;
        satan[tid] = atanf(gw / (gh + CEPS));
        float area = fmaxf(gw, 0.f) * fmaxf(gh, 0.f);
        int lab = (int)lf;
        svld[tid] = (lab >= 0 && area > 0.f) ? 1 : 0;
        slab[tid] = lab < 0 ? 0 : lab;
    }
    __syncthreads();
    int n = blockIdx.x * 256 + tid;
    if (n >= Nv) return;
    size_t bn = (size_t)b * Nv + n;
    unsigned msk = selmask[bn];
    if (!msk) { gtf[bn] = -1; amv[bn] = 0.f; crv[bn] = 0.f; return; }
    float4 p = reinterpret_cast<const float4*>(bdec)[bn];
    float pw = p.z - p.x, ph = p.w - p.y;
    float pwh = pw * ph;
    float patan = atanf(pw / (ph + CEPS));
    int g;
    if (__popc(msk) > 1) {
        // lazy best = argmax_m clip(ciou,0), first-max tiebreak (unmasked)
        float bo = -1.f; g = 0;
        for (int m = 0; m < MGT; ++m) {
            float ov = fmaxf(ciou_pre(sx1[m], sy1[m], sx2[m], sy2[m],
                                      swh[m], satan[m],
                                      p.x, p.y, p.z, p.w, pwh, patan), 0.f);
            if (ov > bo) { bo = ov; g = m; }
        }
    } else {
        g = __ffs(msk) - 1;
    }
    float cr = ciou_pre(sx1[g], sy1[g], sx2[g], sy2[g], swh[g], satan[g],
                        p.x, p.y, p.z, p.w, pwh, patan);
    float ov = fmaxf(cr, 0.f);
    float al = 0.f;
    if (svld[g]) {
        float2 a = reinterpret_cast<const float2*>(anc)[n];
        float mn = fminf(fminf(a.x - sx1[g], a.y - sy1[g]),
                         fminf(sx2[g] - a.x, sy2[g] - a.y));
        if (mn > TEPS && ov > 0.f) {
            float s = sigm_fast(cls[bn * NCLS + slab[g]]);
            float o2 = ov * ov;
            al = __builtin_sqrtf(s) * o2 * o2 * o2;
        }
    }
    gtf[bn] = g; amv[bn] = al; crv[bn] = cr;
    atomicMax(&pos_al[b * MGT + g], __float_as_uint(al));
    atomicMax(&pos_ov[b * MGT + g], __float_as_uint(ov));
}

// ---- fused: BCE cls loss + (pos==0) IoU/DFL terms + last-block final reduce ----
__global__ __launch_bounds__(256) void k_fused(const float* __restrict__ cls,
                                               const float* __restrict__ bdist,
                                               const float* __restrict__ tgt,
                                               const float* __restrict__ anc,
                                               const float* __restrict__ strd,
                                               const int* __restrict__ gtf,
                                               const float* __restrict__ amv,
                                               const float* __restrict__ crv,
                                               const unsigned* __restrict__ pos_al,
                                               const unsigned* __restrict__ pos_ov,
                                               float* __restrict__ p_cls,
                                               float* __restrict__ p_tss,
                                               float* __restrict__ p_iou,
                                               float* __restrict__ p_dfl,
                                               unsigned* __restrict__ done,
                                               float* __restrict__ out,
                                               int total4, int stride_t, int Nv, int Bv) {
    __shared__ float r0[256], r1[256], r2[256], r3[256];
    __shared__ int last_s;
    int tid = threadIdx.x;
    float s_cls = 0.f, s_tss = 0.f, s_iou = 0.f, s_dfl = 0.f;
    for (int i4 = blockIdx.x * 256 + tid; i4 < total4; i4 += stride_t) {
        int bn = i4 / 20;  // 20 float4 per 80-class row
        int pos = i4 - bn * 20;
        int b = bn / Nv;
        int g = gtf[bn];
        float nv = 0.f;
        int tlab = -1;
        if (g >= 0) {
            float pa = __uint_as_float(pos_al[b * MGT + g]);
            float po = __uint_as_float(pos_ov[b * MGT + g]);
            nv = amv[bn] * po / (pa + TEPS);
            float lf = tgt[((size_t)b * MGT + g) * 5];
            tlab = lf < 0.f ? 0 : (int)lf;
        }
        float4 x4 = reinterpret_cast<const float4*>(cls)[i4];
        int c0 = pos * 4;
        float xs[4] = {x4.x, x4.y, x4.z, x4.w};
#pragma unroll
        for (int e = 0; e < 4; ++e) {
            float x = xs[e];
            float ea = __expf(-fabsf(x));        // shared: sigmoid + log1p
            float r = __builtin_amdgcn_rcpf(1.f + ea);
            float p = (x >= 0.f) ? r : ea * r;   // sigmoid(x)
            float t = (c0 + e == tlab) ? nv : 0.f;
            float bce = fmaxf(x, 0.f) - x * t + __logf(1.f + ea);
            float w = (t > 0.f) ? t : 0.75f * p * p;
            s_cls += bce * w;
        }
        if (pos == 0 && nv > 0.f) {  // once per row: tss, IoU, DFL
            s_tss += nv;
            s_iou += (1.f - crv[bn]) * nv;
            int n = bn - b * Nv;
            const float* t5 = tgt + ((size_t)b * MGT + g) * 5;
            float x1 = t5[1], y1 = t5[2], x2 = t5[3], y2 = t5[4];
            float2 a = reinterpret_cast<const float2*>(anc)[n];
            float st = strd[n];
            float ttv[4];
            ttv[0] = (a.x - x1) / st;
            ttv[1] = (a.y - y1) / st;
            ttv[2] = (x2 - a.x) / st;
            ttv[3] = (y2 - a.y) / st;
            const float* bd = bdist + (size_t)bn * 64;
            float acc = 0.f;
#pragma unroll
            for (int k = 0; k < 4; ++k) {
                float t = fminf(fmaxf(ttv[k], 0.f), 14.99f);
                int tl = (int)t;
                float wl = (float)(tl + 1) - t;
                float mx = -3.4e38f;
                for (int j = 0; j < 16; ++j) mx = fmaxf(mx, bd[k * 16 + j]);
                float se = 0.f;
                for (int j = 0; j < 16; ++j) se += __expf(bd[k * 16 + j] - mx);
                float lse = mx + __logf(se);
                float ll = bd[k * 16 + tl] - lse;
                float lr = bd[k * 16 + tl + 1] - lse;
                acc += ll * wl + lr * (1.f - wl);
            }
            s_dfl += (-acc * 0.25f) * nv;
        }
    }
    r0[tid] = s_cls; r1[tid] = s_tss; r2[tid] = s_iou; r3[tid] = s_dfl;
    __syncthreads();
    for (int s = 128; s > 0; s >>= 1) {
        if (tid < s) { r0[tid] += r0[tid + s]; r1[tid] += r1[tid + s];
                       r2[tid] += r2[tid + s]; r3[tid] += r3[tid + s]; }
        __syncthreads();
    }
    if (tid == 0) {
        int bid = blockIdx.x;
        p_cls[bid] = r0[0]; p_tss[bid] = r1[0];
        p_iou[bid] = r2[0]; p_dfl[bid] = r3[0];
        __threadfence();  // release partials device-wide
        unsigned prev = atomicAdd(done, 1u);
        last_s = (prev == gridDim.x - 1) ? 1 : 0;
    }
    __syncthreads();
    if (last_s) {  // deterministic fixed-order final reduce
        __threadfence();  // acquire
        volatile const float* vc = p_cls;
        volatile const float* vt = p_tss;
        volatile const float* vi = p_iou;
        volatile const float* vd = p_dfl;
        int nbk = gridDim.x;
        float a0 = 0.f, a1 = 0.f, a2 = 0.f, a3 = 0.f;
        for (int i = tid; i < nbk; i += 256) {
            a0 += vc[i]; a1 += vt[i]; a2 += vi[i]; a3 += vd[i];
        }
        r0[tid] = a0; r1[tid] = a1; r2[tid] = a2; r3[tid] = a3;
        __syncthreads();
        for (int s = 128; s > 0; s >>= 1) {
            if (tid < s) { r0[tid] += r0[tid + s]; r1[tid] += r1[tid + s];
                           r2[tid] += r2[tid + s]; r3[tid] += r3[tid + s]; }
            __syncthreads();
        }
        if (tid == 0) {
            float tss = fmaxf(r1[0], 1.f);
            float lcls = 0.5f * r0[0] / tss;
            float liou = 7.5f * r2[0] / tss;
            float ldfl = 1.5f * r3[0] / tss;
            out[0] = (lcls + liou + ldfl) * (float)Bv;
            out[1] = lcls;
            out[2] = liou;
            out[3] = ldfl;
        }
    }
}

extern "C" void kernel_launch(void* const* d_in, const int* in_sizes, int n_in,
                              void* d_out, int out_size, void* d_ws, size_t ws_size,
                              hipStream_t stream) {
    const float* cls = (const float*)d_in[0];
    const float* bdist = (const float*)d_in[1];
    const float* bdec = (const float*)d_in[2];
    const float* tgt = (const float*)d_in[3];
    const float* anc = (const float*)d_in[4];
    const float* strd = (const float*)d_in[5];
    int Nv = in_sizes[4] / 2;
    int Bv = in_sizes[3] / (MGT * 5);
    size_t nBN = (size_t)Bv * Nv;
    int gx = (Nv + 255) / 256;
    int nbm = Bv * MGT;
    int total4 = (int)(nBN * (NCLS / 4));
    int ncb = 2048;
    if ((long long)ncb * 256 > (long long)total4) ncb = (total4 + 255) / 256;

    char* base = (char*)d_ws;
    size_t off = 0;
    unsigned* selmask = (unsigned*)(base + off); off += nBN * 4;
    unsigned* pos_al = (unsigned*)(base + off); off += (size_t)nbm * 4;
    unsigned* pos_ov = (unsigned*)(base + off); off += (size_t)nbm * 4;
    unsigned* cntv = (unsigned*)(base + off); off += (size_t)nbm * 4;
    unsigned* done = (unsigned*)(base + off); off += 8;  // zeroed with cntv
    size_t zlen = (size_t)nbm * 4 + 8;
    int* gtfv = (int*)(base + off); off += nBN * 4;
    float* amv = (float*)(base + off); off += nBN * 4;
    float* crvv = (float*)(base + off); off += nBN * 4;
    float* p_tss = (float*)(base + off); off += (size_t)ncb * 4;
    float* p_iou = (float*)(base + off); off += (size_t)ncb * 4;
    float* p_dfl = (float*)(base + off); off += (size_t)ncb * 4;
    float* p_cls = (float*)(base + off); off += (size_t)ncb * 4;
    off = (off + 7) & ~(size_t)7;  // align for u64
    unsigned long long* cand = (unsigned long long*)(base + off);
    size_t remain = (ws_size > off) ? (ws_size - off) : 0;
    int cap = (int)(remain / ((size_t)nbm * 8));
    if (cap > CAPMAX) cap = CAPMAX;
    if (cap < 1) cap = 1;

    dim3 grid(gx, Bv);
    hipMemsetAsync(cntv, 0, zlen, stream);
    k_cand<<<grid, 256, 0, stream>>>(cls, bdec, tgt, anc, cand, cntv,
                                     selmask, pos_al, pos_ov, Nv, cap);
    k_topk2<<<nbm, 256, 0, stream>>>(cand, cntv, selmask, Nv, cap);
    k_resolve<<<grid, 256, 0, stream>>>(cls, bdec, tgt, anc, selmask,
                                        gtfv, amv, crvv, pos_al, pos_ov, Nv);
    k_fused<<<ncb, 256, 0, stream>>>(cls, bdist, tgt, anc, strd,
                                     gtfv, amv, crvv, pos_al, pos_ov,
                                     p_cls, p_tss, p_iou, p_dfl, done,
                                     (float*)d_out, total4, ncb * 256, Nv, Bv);
}

// Round 14
// 176.332 us; speedup vs baseline: 1.0337x; 1.0337x over previous
//
#include <hip/hip_runtime.h>
#include <math.h>

#define MGT 32
#define NCLS 80
#define TEPS 1e-9f
#define CEPS 1e-7f
#define CAPMAX 4096

// hoisted-precompute CIoU: awh=w1*h1, aatan=atan(w1/(h1+eps)) for box a (gt),
// bwh/batan likewise for box b (pred). Bit-identical to the reference op order.
__device__ __forceinline__ float ciou_pre(float ax1, float ay1, float ax2, float ay2,
                                          float awh, float aatan,
                                          float bx1, float by1, float bx2, float by2,
                                          float bwh, float batan) {
    float iw = fmaxf(fminf(ax2, bx2) - fmaxf(ax1, bx1), 0.f);
    float ih = fmaxf(fminf(ay2, by2) - fmaxf(ay1, by1), 0.f);
    float inter = iw * ih;
    float uni = awh + bwh - inter + CEPS;
    float iou = inter / uni;
    float cw = fmaxf(ax2, bx2) - fminf(ax1, bx1);
    float ch = fmaxf(ay2, by2) - fminf(ay1, by1);
    float c2 = cw * cw + ch * ch + CEPS;
    float dx = bx1 + bx2 - ax1 - ax2;
    float dy = by1 + by2 - ay1 - ay2;
    float rho2 = (dx * dx + dy * dy) * 0.25f;
    float dv = batan - aatan;
    float v = 0.405284734569351f * dv * dv;  // 4/pi^2
    float alpha = v / (v - iou + (1.f + CEPS));
    return iou - (rho2 / c2 + v * alpha);
}

__device__ __forceinline__ float sigm_fast(float x) {
    return __builtin_amdgcn_rcpf(1.f + __expf(-x));
}

// ---- kernel: sparse align -> compact per-(b,m) candidate lists; zero-inits ----
// key = bits(al)<<32 | ~n : exact (max-val, min-idx) order; only al>0 appended.
__global__ __launch_bounds__(256) void k_cand(const float* __restrict__ cls,
                                              const float* __restrict__ bdec,
                                              const float* __restrict__ tgt,
                                              const float* __restrict__ anc,
                                              unsigned long long* __restrict__ cand,
                                              unsigned* __restrict__ cnt,
                                              unsigned* __restrict__ selmask,
                                              unsigned* __restrict__ pos_al,
                                              unsigned* __restrict__ pos_ov,
                                              int Nv, int cap) {
    __shared__ float sx1[MGT], sy1[MGT], sx2[MGT], sy2[MGT];
    __shared__ float swh[MGT], satan[MGT];
    __shared__ int slab[MGT], svld[MGT];
    int b = blockIdx.y, tid = threadIdx.x;
    if (tid < MGT) {
        const float* t = tgt + ((size_t)b * MGT + tid) * 5;
        float lf = t[0];
        float x1 = t[1], y1 = t[2], x2 = t[3], y2 = t[4];
        sx1[tid] = x1; sy1[tid] = y1; sx2[tid] = x2; sy2[tid] = y2;
        float gw = x2 - x1, gh = y2 - y1;
        swh[tid] = gw * gh;
        satan[tid] = atanf(gw / (gh + CEPS));
        float area = fmaxf(gw, 0.f) * fmaxf(gh, 0.f);
        int lab = (int)lf;
        svld[tid] = (lab >= 0 && area > 0.f) ? 1 : 0;
        slab[tid] = lab < 0 ? 0 : lab;
        if (blockIdx.x == 0) {  // zero pos maxes once per batch-row
            pos_al[b * MGT + tid] = 0u;
            pos_ov[b * MGT + tid] = 0u;
        }
    }
    __syncthreads();
    int n = blockIdx.x * 256 + tid;
    if (n >= Nv) return;
    size_t bn = (size_t)b * Nv + n;
    selmask[bn] = 0u;  // stream-ordered before k_topk2 ORs
    float4 p = reinterpret_cast<const float4*>(bdec)[bn];
    float2 a = reinterpret_cast<const float2*>(anc)[n];
    const float* crow = cls + bn * NCLS;
    float pw = p.z - p.x, ph = p.w - p.y;
    float pwh = pw * ph;
    float patan = 0.f; bool have_patan = false;
    int lane = tid & 63;
    for (int m = 0; m < MGT; ++m) {
        float al = 0.f;
        if (svld[m]) {
            float mn = fminf(fminf(a.x - sx1[m], a.y - sy1[m]),
                             fminf(sx2[m] - a.x, sy2[m] - a.y));
            if (mn > TEPS) {  // sparse: ~2% of pairs reach CIoU
                if (!have_patan) { patan = atanf(pw / (ph + CEPS)); have_patan = true; }
                float ov = fmaxf(ciou_pre(sx1[m], sy1[m], sx2[m], sy2[m],
                                          swh[m], satan[m],
                                          p.x, p.y, p.z, p.w, pwh, patan), 0.f);
                if (ov > 0.f) {
                    float s = sigm_fast(crow[slab[m]]);
                    float o2 = ov * ov;
                    al = __builtin_sqrtf(s) * o2 * o2 * o2;  // s^0.5 * ov^6
                }
            }
        }
        // wave-aggregated append (order within list is irrelevant: set semantics)
        unsigned long long msk = __ballot(al > 0.f);
        if (msk) {
            int leader = __ffsll((long long)msk) - 1;
            unsigned base = 0;
            if (lane == leader)
                base = atomicAdd(&cnt[b * MGT + m], (unsigned)__popcll(msk));
            base = __shfl(base, leader, 64);
            if (al > 0.f) {
                unsigned rank = (unsigned)__popcll(msk & ((1ull << lane) - 1ull));
                unsigned idx = base + rank;
                if ((int)idx < cap) {
                    unsigned long long key =
                        (((unsigned long long)__float_as_uint(al)) << 32) |
                        (unsigned)(0xFFFFFFFFu - (unsigned)n);
                    cand[((size_t)b * MGT + m) * cap + idx] = key;
                }
            }
        }
    }
}

// ---- kernel: per-(b,m) top-10 from compact list -> selmask (register queue) ----
__global__ __launch_bounds__(256) void k_topk2(const unsigned long long* __restrict__ cand,
                                               const unsigned* __restrict__ cnt,
                                               unsigned* __restrict__ selmask,
                                               int Nv, int cap) {
    __shared__ unsigned long long warp_r[4];
    __shared__ unsigned long long winner_s;
    int bid = blockIdx.x;          // = b*MGT + m
    int b = bid / MGT, m = bid - b * MGT;
    int tid = threadIdx.x;
    int total = (int)cnt[bid];
    if (total > cap) total = cap;
    const unsigned long long* row = cand + (size_t)bid * cap;
    unsigned long long v[10];  // ascending; v[9] = max
#pragma unroll
    for (int i = 0; i < 10; ++i) v[i] = 0ull;
    for (int i = tid; i < total; i += 256) {
        unsigned long long key = row[i];
        if (key > v[0]) {  // sorted ascending insert
            unsigned long long cv = key; bool placed = false;
#pragma unroll
            for (int j = 0; j < 9; ++j) {
                if (!placed) {
                    if (cv > v[j + 1]) { v[j] = v[j + 1]; }
                    else { v[j] = cv; placed = true; }
                }
            }
            if (!placed) v[9] = cv;
        }
    }
    for (int r = 0; r < 10; ++r) {
        unsigned long long cand_k = v[9];
        unsigned long long w = cand_k;
#pragma unroll
        for (int s = 32; s > 0; s >>= 1) {
            unsigned long long o = __shfl_xor(w, s, 64);
            w = (o > w) ? o : w;
        }
        if ((tid & 63) == 0) warp_r[tid >> 6] = w;
        __syncthreads();
        if (tid == 0) {
            unsigned long long ww = warp_r[0];
            ww = (warp_r[1] > ww) ? warp_r[1] : ww;
            ww = (warp_r[2] > ww) ? warp_r[2] : ww;
            ww = (warp_r[3] > ww) ? warp_r[3] : ww;
            winner_s = ww;
            float wv = __uint_as_float((unsigned)(ww >> 32));
            if (wv > TEPS) {
                unsigned wi = 0xFFFFFFFFu - (unsigned)(ww & 0xFFFFFFFFull);
                atomicOr(&selmask[(size_t)b * Nv + wi], 1u << m);
            }
        }
        __syncthreads();
        unsigned long long win = winner_s;
        if (win == 0ull) break;  // no more positive candidates
        if (cand_k == win) {     // unique owner (idx embedded): pop max, shift up
#pragma unroll
            for (int j = 9; j > 0; --j) v[j] = v[j - 1];
            v[0] = 0ull;
        }
        __syncthreads();
    }
}

// ---- kernel: resolve multi-assignment (lazy bestm), per-anchor gt/align/ciou ----
__global__ __launch_bounds__(256) void k_resolve(const float* __restrict__ cls,
                                                 const float* __restrict__ bdec,
                                                 const float* __restrict__ tgt,
                                                 const float* __restrict__ anc,
                                                 const unsigned* __restrict__ selmask,
                                                 int* __restrict__ gtf,
                                                 float* __restrict__ amv,
                                                 float* __restrict__ crv,
                                                 unsigned* __restrict__ pos_al,
                                                 unsigned* __restrict__ pos_ov, int Nv) {
    __shared__ float sx1[MGT], sy1[MGT], sx2[MGT], sy2[MGT];
    __shared__ float swh[MGT], satan[MGT];
    __shared__ int slab[MGT], svld[MGT];
    int b = blockIdx.y, tid = threadIdx.x;
    if (tid < MGT) {
        const float* t = tgt + ((size_t)b * MGT + tid) * 5;
        float lf = t[0];
        float x1 = t[1], y1 = t[2], x2 = t[3], y2 = t[4];
        sx1[tid] = x1; sy1[tid] = y1; sx2[tid] = x2; sy2[tid] = y2;
        float gw = x2 - x1, gh = y2 - y1;
        swh[tid] = gw * gh;
        satan[tid] = atanf(gw / (gh + CEPS));
        float area = fmaxf(gw, 0.f) * fmaxf(gh, 0.f);
        int lab = (int)lf;
        svld[tid] = (lab >= 0 && area > 0.f) ? 1 : 0;
        slab[tid] = lab < 0 ? 0 : lab;
    }
    __syncthreads();
    int n = blockIdx.x * 256 + tid;
    if (n >= Nv) return;
    size_t bn = (size_t)b * Nv + n;
    unsigned msk = selmask[bn];
    if (!msk) { gtf[bn] = -1; amv[bn] = 0.f; crv[bn] = 0.f; return; }
    float4 p = reinterpret_cast<const float4*>(bdec)[bn];
    float pw = p.z - p.x, ph = p.w - p.y;
    float pwh = pw * ph;
    float patan = atanf(pw / (ph + CEPS));
    int g;
    if (__popc(msk) > 1) {
        // lazy best = argmax_m clip(ciou,0), first-max tiebreak (unmasked)
        float bo = -1.f; g = 0;
        for (int m = 0; m < MGT; ++m) {
            float ov = fmaxf(ciou_pre(sx1[m], sy1[m], sx2[m], sy2[m],
                                      swh[m], satan[m],
                                      p.x, p.y, p.z, p.w, pwh, patan), 0.f);
            if (ov > bo) { bo = ov; g = m; }
        }
    } else {
        g = __ffs(msk) - 1;
    }
    float cr = ciou_pre(sx1[g], sy1[g], sx2[g], sy2[g], swh[g], satan[g],
                        p.x, p.y, p.z, p.w, pwh, patan);
    float ov = fmaxf(cr, 0.f);
    float al = 0.f;
    if (svld[g]) {
        float2 a = reinterpret_cast<const float2*>(anc)[n];
        float mn = fminf(fminf(a.x - sx1[g], a.y - sy1[g]),
                         fminf(sx2[g] - a.x, sy2[g] - a.y));
        if (mn > TEPS && ov > 0.f) {
            float s = sigm_fast(cls[bn * NCLS + slab[g]]);
            float o2 = ov * ov;
            al = __builtin_sqrtf(s) * o2 * o2 * o2;
        }
    }
    gtf[bn] = g; amv[bn] = al; crv[bn] = cr;
    atomicMax(&pos_al[b * MGT + g], __float_as_uint(al));
    atomicMax(&pos_ov[b * MGT + g], __float_as_uint(ov));
}

// ---- fused2: row-chunked two-phase; phase1 per-row nv/tlab (+IoU/DFL),
//      phase2 coalesced BCE sweep; last-block deterministic final reduce ----
__global__ __launch_bounds__(256) void k_fused2(const float* __restrict__ cls,
                                                const float* __restrict__ bdist,
                                                const float* __restrict__ tgt,
                                                const float* __restrict__ anc,
                                                const float* __restrict__ strd,
                                                const int* __restrict__ gtf,
                                                const float* __restrict__ amv,
                                                const float* __restrict__ crv,
                                                const unsigned* __restrict__ pos_al,
                                                const unsigned* __restrict__ pos_ov,
                                                float* __restrict__ p_cls,
                                                float* __restrict__ p_tss,
                                                float* __restrict__ p_iou,
                                                float* __restrict__ p_dfl,
                                                unsigned* __restrict__ done,
                                                float* __restrict__ out,
                                                int nrows, int Nv, int Bv) {
    __shared__ float s_nv[256];
    __shared__ int s_tl[256];
    __shared__ float r0[256], r1[256], r2[256], r3[256];
    __shared__ int last_s;
    int tid = threadIdx.x;
    int row0 = blockIdx.x * 256;
    int row = row0 + tid;
    float s_tss = 0.f, s_iou = 0.f, s_dfl = 0.f;
    // ---- phase 1: per-row nv/tlab once; rare IoU/DFL terms ----
    float nv = 0.f; int tl = -1;
    if (row < nrows) {
        int g = gtf[row];
        if (g >= 0) {
            int b = row / Nv;  // once per row
            float pa = __uint_as_float(pos_al[b * MGT + g]);
            float po = __uint_as_float(pos_ov[b * MGT + g]);
            nv = amv[row] * po / (pa + TEPS);
            const float* t5 = tgt + ((size_t)b * MGT + g) * 5;
            float lf = t5[0];
            tl = lf < 0.f ? 0 : (int)lf;
            if (nv > 0.f) {
                s_tss = nv;
                s_iou = (1.f - crv[row]) * nv;
                int n = row - b * Nv;
                float x1 = t5[1], y1 = t5[2], x2 = t5[3], y2 = t5[4];
                float2 a = reinterpret_cast<const float2*>(anc)[n];
                float st = strd[n];
                float ttv[4];
                ttv[0] = (a.x - x1) / st;
                ttv[1] = (a.y - y1) / st;
                ttv[2] = (x2 - a.x) / st;
                ttv[3] = (y2 - a.y) / st;
                const float* bd = bdist + (size_t)row * 64;
                float acc = 0.f;
#pragma unroll
                for (int k = 0; k < 4; ++k) {
                    float t = fminf(fmaxf(ttv[k], 0.f), 14.99f);
                    int tli = (int)t;
                    float wl = (float)(tli + 1) - t;
                    float mx = -3.4e38f;
                    for (int j = 0; j < 16; ++j) mx = fmaxf(mx, bd[k * 16 + j]);
                    float se = 0.f;
                    for (int j = 0; j < 16; ++j) se += __expf(bd[k * 16 + j] - mx);
                    float lse = mx + __logf(se);
                    float ll = bd[k * 16 + tli] - lse;
                    float lr = bd[k * 16 + tli + 1] - lse;
                    acc += ll * wl + lr * (1.f - wl);
                }
                s_dfl = (-acc * 0.25f) * nv;
            }
        }
    }
    s_nv[tid] = nv; s_tl[tid] = tl;
    __syncthreads();
    // ---- phase 2: coalesced sweep of this block's 256 rows x 20 float4 ----
    float s_cls = 0.f;
    int nrow_blk = nrows - row0;
    if (nrow_blk > 256) nrow_blk = 256;
    int tot = nrow_blk * 20;
    const float4* cbase = reinterpret_cast<const float4*>(cls) + (size_t)row0 * 20;
    for (int i = tid; i < tot; i += 256) {
        int r = i / 20;            // compile-time divisor: magic-mul
        int pos = i - r * 20;
        float4 x4 = cbase[i];
        float rnv = s_nv[r];
        int rtl = s_tl[r];
        int c0 = pos * 4;
        float xs[4] = {x4.x, x4.y, x4.z, x4.w};
#pragma unroll
        for (int e = 0; e < 4; ++e) {
            float x = xs[e];
            float ea = __expf(-fabsf(x));        // shared: sigmoid + log1p
            float rr = __builtin_amdgcn_rcpf(1.f + ea);
            float p = (x >= 0.f) ? rr : ea * rr; // sigmoid(x)
            float t = (c0 + e == rtl) ? rnv : 0.f;
            float bce = fmaxf(x, 0.f) - x * t + __logf(1.f + ea);
            float w = (t > 0.f) ? t : 0.75f * p * p;
            s_cls += bce * w;
        }
    }
    r0[tid] = s_cls; r1[tid] = s_tss; r2[tid] = s_iou; r3[tid] = s_dfl;
    __syncthreads();
    for (int s = 128; s > 0; s >>= 1) {
        if (tid < s) { r0[tid] += r0[tid + s]; r1[tid] += r1[tid + s];
                       r2[tid] += r2[tid + s]; r3[tid] += r3[tid + s]; }
        __syncthreads();
    }
    if (tid == 0) {
        int bid = blockIdx.x;
        p_cls[bid] = r0[0]; p_tss[bid] = r1[0];
        p_iou[bid] = r2[0]; p_dfl[bid] = r3[0];
        __threadfence();  // release partials device-wide
        unsigned prev = atomicAdd(done, 1u);
        last_s = (prev == gridDim.x - 1) ? 1 : 0;
    }
    __syncthreads();
    if (last_s) {  // deterministic fixed-order final reduce
        __threadfence();  // acquire
        volatile const float* vc = p_cls;
        volatile const float* vt = p_tss;
        volatile const float* vi = p_iou;
        volatile const float* vd = p_dfl;
        int nbk = gridDim.x;
        float a0 = 0.f, a1 = 0.f, a2 = 0.f, a3 = 0.f;
        for (int i = tid; i < nbk; i += 256) {
            a0 += vc[i]; a1 += vt[i]; a2 += vi[i]; a3 += vd[i];
        }
        r0[tid] = a0; r1[tid] = a1; r2[tid] = a2; r3[tid] = a3;
        __syncthreads();
        for (int s = 128; s > 0; s >>= 1) {
            if (tid < s) { r0[tid] += r0[tid + s]; r1[tid] += r1[tid + s];
                           r2[tid] += r2[tid + s]; r3[tid] += r3[tid + s]; }
            __syncthreads();
        }
        if (tid == 0) {
            float tss = fmaxf(r1[0], 1.f);
            float lcls = 0.5f * r0[0] / tss;
            float liou = 7.5f * r2[0] / tss;
            float ldfl = 1.5f * r3[0] / tss;
            out[0] = (lcls + liou + ldfl) * (float)Bv;
            out[1] = lcls;
            out[2] = liou;
            out[3] = ldfl;
        }
    }
}

extern "C" void kernel_launch(void* const* d_in, const int* in_sizes, int n_in,
                              void* d_out, int out_size, void* d_ws, size_t ws_size,
                              hipStream_t stream) {
    const float* cls = (const float*)d_in[0];
    const float* bdist = (const float*)d_in[1];
    const float* bdec = (const float*)d_in[2];
    const float* tgt = (const float*)d_in[3];
    const float* anc = (const float*)d_in[4];
    const float* strd = (const float*)d_in[5];
    int Nv = in_sizes[4] / 2;
    int Bv = in_sizes[3] / (MGT * 5);
    size_t nBN = (size_t)Bv * Nv;
    int gx = (Nv + 255) / 256;
    int nbm = Bv * MGT;
    int nrows = (int)nBN;
    int nfb = (nrows + 255) / 256;  // fused2 grid

    char* base = (char*)d_ws;
    size_t off = 0;
    unsigned* selmask = (unsigned*)(base + off); off += nBN * 4;
    unsigned* pos_al = (unsigned*)(base + off); off += (size_t)nbm * 4;
    unsigned* pos_ov = (unsigned*)(base + off); off += (size_t)nbm * 4;
    unsigned* cntv = (unsigned*)(base + off); off += (size_t)nbm * 4;
    unsigned* done = (unsigned*)(base + off); off += 8;  // zeroed with cntv
    size_t zlen = (size_t)nbm * 4 + 8;
    int* gtfv = (int*)(base + off); off += nBN * 4;
    float* amv = (float*)(base + off); off += nBN * 4;
    float* crvv = (float*)(base + off); off += nBN * 4;
    float* p_tss = (float*)(base + off); off += (size_t)nfb * 4;
    float* p_iou = (float*)(base + off); off += (size_t)nfb * 4;
    float* p_dfl = (float*)(base + off); off += (size_t)nfb * 4;
    float* p_cls = (float*)(base + off); off += (size_t)nfb * 4;
    off = (off + 7) & ~(size_t)7;  // align for u64
    unsigned long long* cand = (unsigned long long*)(base + off);
    size_t remain = (ws_size > off) ? (ws_size - off) : 0;
    int cap = (int)(remain / ((size_t)nbm * 8));
    if (cap > CAPMAX) cap = CAPMAX;
    if (cap < 1) cap = 1;

    dim3 grid(gx, Bv);
    hipMemsetAsync(cntv, 0, zlen, stream);
    k_cand<<<grid, 256, 0, stream>>>(cls, bdec, tgt, anc, cand, cntv,
                                     selmask, pos_al, pos_ov, Nv, cap);
    k_topk2<<<nbm, 256, 0, stream>>>(cand, cntv, selmask, Nv, cap);
    k_resolve<<<grid, 256, 0, stream>>>(cls, bdec, tgt, anc, selmask,
                                        gtfv, amv, crvv, pos_al, pos_ov, Nv);
    k_fused2<<<nfb, 256, 0, stream>>>(cls, bdist, tgt, anc, strd,
                                      gtfv, amv, crvv, pos_al, pos_ov,
                                      p_cls, p_tss, p_iou, p_dfl, done,
                                      (float*)d_out, nrows, Nv, Bv);
}

// Round 16
// 120.955 us; speedup vs baseline: 1.5070x; 1.4578x over previous
//
#include <hip/hip_runtime.h>
#include <math.h>

#define MGT 32
#define NCLS 80
#define TEPS 1e-9f
#define CEPS 1e-7f
#define CAPMAX 4096

// hoisted-precompute CIoU: awh=w1*h1, aatan=atan(w1/(h1+eps)) for box a (gt),
// bwh/batan likewise for box b (pred). Bit-identical to the reference op order.
__device__ __forceinline__ float ciou_pre(float ax1, float ay1, float ax2, float ay2,
                                          float awh, float aatan,
                                          float bx1, float by1, float bx2, float by2,
                                          float bwh, float batan) {
    float iw = fmaxf(fminf(ax2, bx2) - fmaxf(ax1, bx1), 0.f);
    float ih = fmaxf(fminf(ay2, by2) - fmaxf(ay1, by1), 0.f);
    float inter = iw * ih;
    float uni = awh + bwh - inter + CEPS;
    float iou = inter / uni;
    float cw = fmaxf(ax2, bx2) - fminf(ax1, bx1);
    float ch = fmaxf(ay2, by2) - fminf(ay1, by1);
    float c2 = cw * cw + ch * ch + CEPS;
    float dx = bx1 + bx2 - ax1 - ax2;
    float dy = by1 + by2 - ay1 - ay2;
    float rho2 = (dx * dx + dy * dy) * 0.25f;
    float dv = batan - aatan;
    float v = 0.405284734569351f * dv * dv;  // 4/pi^2
    float alpha = v / (v - iou + (1.f + CEPS));
    return iou - (rho2 / c2 + v * alpha);
}

__device__ __forceinline__ float sigm_fast(float x) {
    return __builtin_amdgcn_rcpf(1.f + __expf(-x));
}

// ---- kernel: sparse align -> compact per-(b,m) candidate lists; zero-inits ----
// key = bits(al)<<32 | ~n : exact (max-val, min-idx) order; only al>0 appended.
__global__ __launch_bounds__(256) void k_cand(const float* __restrict__ cls,
                                              const float* __restrict__ bdec,
                                              const float* __restrict__ tgt,
                                              const float* __restrict__ anc,
                                              unsigned long long* __restrict__ cand,
                                              unsigned* __restrict__ cnt,
                                              unsigned* __restrict__ selmask,
                                              unsigned* __restrict__ pos_al,
                                              unsigned* __restrict__ pos_ov,
                                              int Nv, int cap) {
    __shared__ float sx1[MGT], sy1[MGT], sx2[MGT], sy2[MGT];
    __shared__ float swh[MGT], satan[MGT];
    __shared__ int slab[MGT], svld[MGT];
    int b = blockIdx.y, tid = threadIdx.x;
    if (tid < MGT) {
        const float* t = tgt + ((size_t)b * MGT + tid) * 5;
        float lf = t[0];
        float x1 = t[1], y1 = t[2], x2 = t[3], y2 = t[4];
        sx1[tid] = x1; sy1[tid] = y1; sx2[tid] = x2; sy2[tid] = y2;
        float gw = x2 - x1, gh = y2 - y1;
        swh[tid] = gw * gh;
        satan[tid] = atanf(gw / (gh + CEPS));
        float area = fmaxf(gw, 0.f) * fmaxf(gh, 0.f);
        int lab = (int)lf;
        svld[tid] = (lab >= 0 && area > 0.f) ? 1 : 0;
        slab[tid] = lab < 0 ? 0 : lab;
        if (blockIdx.x == 0) {  // zero pos maxes once per batch-row
            pos_al[b * MGT + tid] = 0u;
            pos_ov[b * MGT + tid] = 0u;
        }
    }
    __syncthreads();
    int n = blockIdx.x * 256 + tid;
    if (n >= Nv) return;
    size_t bn = (size_t)b * Nv + n;
    selmask[bn] = 0u;  // stream-ordered before k_topk2 ORs
    float4 p = reinterpret_cast<const float4*>(bdec)[bn];
    float2 a = reinterpret_cast<const float2*>(anc)[n];
    const float* crow = cls + bn * NCLS;
    float pw = p.z - p.x, ph = p.w - p.y;
    float pwh = pw * ph;
    float patan = 0.f; bool have_patan = false;
    int lane = tid & 63;
    for (int m = 0; m < MGT; ++m) {
        float al = 0.f;
        if (svld[m]) {
            float mn = fminf(fminf(a.x - sx1[m], a.y - sy1[m]),
                             fminf(sx2[m] - a.x, sy2[m] - a.y));
            if (mn > TEPS) {  // sparse: ~2% of pairs reach CIoU
                if (!have_patan) { patan = atanf(pw / (ph + CEPS)); have_patan = true; }
                float ov = fmaxf(ciou_pre(sx1[m], sy1[m], sx2[m], sy2[m],
                                          swh[m], satan[m],
                                          p.x, p.y, p.z, p.w, pwh, patan), 0.f);
                if (ov > 0.f) {
                    float s = sigm_fast(crow[slab[m]]);
                    float o2 = ov * ov;
                    al = __builtin_sqrtf(s) * o2 * o2 * o2;  // s^0.5 * ov^6
                }
            }
        }
        // wave-aggregated append (order within list is irrelevant: set semantics)
        unsigned long long msk = __ballot(al > 0.f);
        if (msk) {
            int leader = __ffsll((long long)msk) - 1;
            unsigned base = 0;
            if (lane == leader)
                base = atomicAdd(&cnt[b * MGT + m], (unsigned)__popcll(msk));
            base = __shfl(base, leader, 64);
            if (al > 0.f) {
                unsigned rank = (unsigned)__popcll(msk & ((1ull << lane) - 1ull));
                unsigned idx = base + rank;
                if ((int)idx < cap) {
                    unsigned long long key =
                        (((unsigned long long)__float_as_uint(al)) << 32) |
                        (unsigned)(0xFFFFFFFFu - (unsigned)n);
                    cand[((size_t)b * MGT + m) * cap + idx] = key;
                }
            }
        }
    }
}

// ---- kernel: per-(b,m) top-10 from compact list -> selmask (register queue) ----
__global__ __launch_bounds__(256) void k_topk2(const unsigned long long* __restrict__ cand,
                                               const unsigned* __restrict__ cnt,
                                               unsigned* __restrict__ selmask,
                                               int Nv, int cap) {
    __shared__ unsigned long long warp_r[4];
    __shared__ unsigned long long winner_s;
    int bid = blockIdx.x;          // = b*MGT + m
    int b = bid / MGT, m = bid - b * MGT;
    int tid = threadIdx.x;
    int total = (int)cnt[bid];
    if (total > cap) total = cap;
    const unsigned long long* row = cand + (size_t)bid * cap;
    unsigned long long v[10];  // ascending; v[9] = max
#pragma unroll
    for (int i = 0; i < 10; ++i) v[i] = 0ull;
    for (int i = tid; i < total; i += 256) {
        unsigned long long key = row[i];
        if (key > v[0]) {  // sorted ascending insert
            unsigned long long cv = key; bool placed = false;
#pragma unroll
            for (int j = 0; j < 9; ++j) {
                if (!placed) {
                    if (cv > v[j + 1]) { v[j] = v[j + 1]; }
                    else { v[j] = cv; placed = true; }
                }
            }
            if (!placed) v[9] = cv;
        }
    }
    for (int r = 0; r < 10; ++r) {
        unsigned long long cand_k = v[9];
        unsigned long long w = cand_k;
#pragma unroll
        for (int s = 32; s > 0; s >>= 1) {
            unsigned long long o = __shfl_xor(w, s, 64);
            w = (o > w) ? o : w;
        }
        if ((tid & 63) == 0) warp_r[tid >> 6] = w;
        __syncthreads();
        if (tid == 0) {
            unsigned long long ww = warp_r[0];
            ww = (warp_r[1] > ww) ? warp_r[1] : ww;
            ww = (warp_r[2] > ww) ? warp_r[2] : ww;
            ww = (warp_r[3] > ww) ? warp_r[3] : ww;
            winner_s = ww;
            float wv = __uint_as_float((unsigned)(ww >> 32));
            if (wv > TEPS) {
                unsigned wi = 0xFFFFFFFFu - (unsigned)(ww & 0xFFFFFFFFull);
                atomicOr(&selmask[(size_t)b * Nv + wi], 1u << m);
            }
        }
        __syncthreads();
        unsigned long long win = winner_s;
        if (win == 0ull) break;  // no more positive candidates
        if (cand_k == win) {     // unique owner (idx embedded): pop max, shift up
#pragma unroll
            for (int j = 9; j > 0; --j) v[j] = v[j - 1];
            v[0] = 0ull;
        }
        __syncthreads();
    }
}

// ---- kernel: resolve multi-assignment (lazy bestm), per-anchor gt/align/ciou ----
__global__ __launch_bounds__(256) void k_resolve(const float* __restrict__ cls,
                                                 const float* __restrict__ bdec,
                                                 const float* __restrict__ tgt,
                                                 const float* __restrict__ anc,
                                                 const unsigned* __restrict__ selmask,
                                                 int* __restrict__ gtf,
                                                 float* __restrict__ amv,
                                                 float* __restrict__ crv,
                                                 unsigned* __restrict__ pos_al,
                                                 unsigned* __restrict__ pos_ov, int Nv) {
    __shared__ float sx1[MGT], sy1[MGT], sx2[MGT], sy2[MGT];
    __shared__ float swh[MGT], satan[MGT];
    __shared__ int slab[MGT], svld[MGT];
    int b = blockIdx.y, tid = threadIdx.x;
    if (tid < MGT) {
        const float* t = tgt + ((size_t)b * MGT + tid) * 5;
        float lf = t[0];
        float x1 = t[1], y1 = t[2], x2 = t[3], y2 = t[4];
        sx1[tid] = x1; sy1[tid] = y1; sx2[tid] = x2; sy2[tid] = y2;
        float gw = x2 - x1, gh = y2 - y1;
        swh[tid] = gw * gh;
        satan[tid] = atanf(gw / (gh + CEPS));
        float area = fmaxf(gw, 0.f) * fmaxf(gh, 0.f);
        int lab = (int)lf;
        svld[tid] = (lab >= 0 && area > 0.f) ? 1 : 0;
        slab[tid] = lab < 0 ? 0 : lab;
    }
    __syncthreads();
    int n = blockIdx.x * 256 + tid;
    if (n >= Nv) return;
    size_t bn = (size_t)b * Nv + n;
    unsigned msk = selmask[bn];
    if (!msk) { gtf[bn] = -1; amv[bn] = 0.f; crv[bn] = 0.f; return; }
    float4 p = reinterpret_cast<const float4*>(bdec)[bn];
    float pw = p.z - p.x, ph = p.w - p.y;
    float pwh = pw * ph;
    float patan = atanf(pw / (ph + CEPS));
    int g;
    if (__popc(msk) > 1) {
        // lazy best = argmax_m clip(ciou,0), first-max tiebreak (unmasked)
        float bo = -1.f; g = 0;
        for (int m = 0; m < MGT; ++m) {
            float ov = fmaxf(ciou_pre(sx1[m], sy1[m], sx2[m], sy2[m],
                                      swh[m], satan[m],
                                      p.x, p.y, p.z, p.w, pwh, patan), 0.f);
            if (ov > bo) { bo = ov; g = m; }
        }
    } else {
        g = __ffs(msk) - 1;
    }
    float cr = ciou_pre(sx1[g], sy1[g], sx2[g], sy2[g], swh[g], satan[g],
                        p.x, p.y, p.z, p.w, pwh, patan);
    float ov = fmaxf(cr, 0.f);
    float al = 0.f;
    if (svld[g]) {
        float2 a = reinterpret_cast<const float2*>(anc)[n];
        float mn = fminf(fminf(a.x - sx1[g], a.y - sy1[g]),
                         fminf(sx2[g] - a.x, sy2[g] - a.y));
        if (mn > TEPS && ov > 0.f) {
            float s = sigm_fast(cls[bn * NCLS + slab[g]]);
            float o2 = ov * ov;
            al = __builtin_sqrtf(s) * o2 * o2 * o2;
        }
    }
    gtf[bn] = g; amv[bn] = al; crv[bn] = cr;
    atomicMax(&pos_al[b * MGT + g], __float_as_uint(al));
    atomicMax(&pos_ov[b * MGT + g], __float_as_uint(ov));
}

// ---- fused3: row-chunked two-phase (NO fence/done protocol);
//      phase1 per-row nv/tlab (+IoU/DFL), phase2 coalesced BCE sweep ----
__global__ __launch_bounds__(256) void k_fused3(const float* __restrict__ cls,
                                                const float* __restrict__ bdist,
                                                const float* __restrict__ tgt,
                                                const float* __restrict__ anc,
                                                const float* __restrict__ strd,
                                                const int* __restrict__ gtf,
                                                const float* __restrict__ amv,
                                                const float* __restrict__ crv,
                                                const unsigned* __restrict__ pos_al,
                                                const unsigned* __restrict__ pos_ov,
                                                float* __restrict__ p_cls,
                                                float* __restrict__ p_tss,
                                                float* __restrict__ p_iou,
                                                float* __restrict__ p_dfl,
                                                int nrows, int Nv) {
    __shared__ float s_nv[256];
    __shared__ int s_tl[256];
    __shared__ float r0[256], r1[256], r2[256], r3[256];
    int tid = threadIdx.x;
    int row0 = blockIdx.x * 256;
    int row = row0 + tid;
    float s_tss = 0.f, s_iou = 0.f, s_dfl = 0.f;
    // ---- phase 1: per-row nv/tlab once; rare IoU/DFL terms ----
    float nv = 0.f; int tl = -1;
    if (row < nrows) {
        int g = gtf[row];
        if (g >= 0) {
            int b = row / Nv;  // once per row
            float pa = __uint_as_float(pos_al[b * MGT + g]);
            float po = __uint_as_float(pos_ov[b * MGT + g]);
            nv = amv[row] * po / (pa + TEPS);
            const float* t5 = tgt + ((size_t)b * MGT + g) * 5;
            float lf = t5[0];
            tl = lf < 0.f ? 0 : (int)lf;
            if (nv > 0.f) {
                s_tss = nv;
                s_iou = (1.f - crv[row]) * nv;
                int n = row - b * Nv;
                float x1 = t5[1], y1 = t5[2], x2 = t5[3], y2 = t5[4];
                float2 a = reinterpret_cast<const float2*>(anc)[n];
                float st = strd[n];
                float ttv[4];
                ttv[0] = (a.x - x1) / st;
                ttv[1] = (a.y - y1) / st;
                ttv[2] = (x2 - a.x) / st;
                ttv[3] = (y2 - a.y) / st;
                const float* bd = bdist + (size_t)row * 64;
                float acc = 0.f;
#pragma unroll
                for (int k = 0; k < 4; ++k) {
                    float t = fminf(fmaxf(ttv[k], 0.f), 14.99f);
                    int tli = (int)t;
                    float wl = (float)(tli + 1) - t;
                    float mx = -3.4e38f;
                    for (int j = 0; j < 16; ++j) mx = fmaxf(mx, bd[k * 16 + j]);
                    float se = 0.f;
                    for (int j = 0; j < 16; ++j) se += __expf(bd[k * 16 + j] - mx);
                    float lse = mx + __logf(se);
                    float ll = bd[k * 16 + tli] - lse;
                    float lr = bd[k * 16 + tli + 1] - lse;
                    acc += ll * wl + lr * (1.f - wl);
                }
                s_dfl = (-acc * 0.25f) * nv;
            }
        }
    }
    s_nv[tid] = nv; s_tl[tid] = tl;
    __syncthreads();
    // ---- phase 2: coalesced sweep of this block's 256 rows x 20 float4 ----
    float s_cls = 0.f;
    int nrow_blk = nrows - row0;
    if (nrow_blk > 256) nrow_blk = 256;
    int tot = nrow_blk * 20;
    const float4* cbase = reinterpret_cast<const float4*>(cls) + (size_t)row0 * 20;
    for (int i = tid; i < tot; i += 256) {
        int r = i / 20;            // compile-time divisor: magic-mul
        int pos = i - r * 20;
        float4 x4 = cbase[i];
        float rnv = s_nv[r];
        int rtl = s_tl[r];
        int c0 = pos * 4;
        float xs[4] = {x4.x, x4.y, x4.z, x4.w};
#pragma unroll
        for (int e = 0; e < 4; ++e) {
            float x = xs[e];
            float ea = __expf(-fabsf(x));        // shared: sigmoid + log1p
            float rr = __builtin_amdgcn_rcpf(1.f + ea);
            float p = (x >= 0.f) ? rr : ea * rr; // sigmoid(x)
            float t = (c0 + e == rtl) ? rnv : 0.f;
            float bce = fmaxf(x, 0.f) - x * t + __logf(1.f + ea);
            float w = (t > 0.f) ? t : 0.75f * p * p;
            s_cls += bce * w;
        }
    }
    r0[tid] = s_cls; r1[tid] = s_tss; r2[tid] = s_iou; r3[tid] = s_dfl;
    __syncthreads();
    for (int s = 128; s > 0; s >>= 1) {
        if (tid < s) { r0[tid] += r0[tid + s]; r1[tid] += r1[tid + s];
                       r2[tid] += r2[tid + s]; r3[tid] += r3[tid + s]; }
        __syncthreads();
    }
    if (tid == 0) {
        int bid = blockIdx.x;
        p_cls[bid] = r0[0]; p_tss[bid] = r1[0];
        p_iou[bid] = r2[0]; p_dfl[bid] = r3[0];
    }
}

// ---- kernel: deterministic final reduce + combine (separate dispatch) ----
__global__ __launch_bounds__(256) void k_final(const float* __restrict__ p_cls,
                                               const float* __restrict__ p_tss,
                                               const float* __restrict__ p_iou,
                                               const float* __restrict__ p_dfl,
                                               int nbk, float* __restrict__ out, int Bv) {
    __shared__ float s0[256], s1[256], s2[256], s3[256];
    int tid = threadIdx.x;
    float a0 = 0.f, a1 = 0.f, a2 = 0.f, a3 = 0.f;
    for (int i = tid; i < nbk; i += 256) {
        a0 += p_cls[i]; a1 += p_tss[i]; a2 += p_iou[i]; a3 += p_dfl[i];
    }
    s0[tid] = a0; s1[tid] = a1; s2[tid] = a2; s3[tid] = a3;
    __syncthreads();
    for (int s = 128; s > 0; s >>= 1) {
        if (tid < s) { s0[tid] += s0[tid + s]; s1[tid] += s1[tid + s];
                       s2[tid] += s2[tid + s]; s3[tid] += s3[tid + s]; }
        __syncthreads();
    }
    if (tid == 0) {
        float tss = fmaxf(s1[0], 1.f);
        float lcls = 0.5f * s0[0] / tss;
        float liou = 7.5f * s2[0] / tss;
        float ldfl = 1.5f * s3[0] / tss;
        out[0] = (lcls + liou + ldfl) * (float)Bv;
        out[1] = lcls;
        out[2] = liou;
        out[3] = ldfl;
    }
}

extern "C" void kernel_launch(void* const* d_in, const int* in_sizes, int n_in,
                              void* d_out, int out_size, void* d_ws, size_t ws_size,
                              hipStream_t stream) {
    const float* cls = (const float*)d_in[0];
    const float* bdist = (const float*)d_in[1];
    const float* bdec = (const float*)d_in[2];
    const float* tgt = (const float*)d_in[3];
    const float* anc = (const float*)d_in[4];
    const float* strd = (const float*)d_in[5];
    int Nv = in_sizes[4] / 2;
    int Bv = in_sizes[3] / (MGT * 5);
    size_t nBN = (size_t)Bv * Nv;
    int gx = (Nv + 255) / 256;
    int nbm = Bv * MGT;
    int nrows = (int)nBN;
    int nfb = (nrows + 255) / 256;  // fused3 grid

    char* base = (char*)d_ws;
    size_t off = 0;
    unsigned* selmask = (unsigned*)(base + off); off += nBN * 4;
    unsigned* pos_al = (unsigned*)(base + off); off += (size_t)nbm * 4;
    unsigned* pos_ov = (unsigned*)(base + off); off += (size_t)nbm * 4;
    unsigned* cntv = (unsigned*)(base + off); off += (size_t)nbm * 4;
    int* gtfv = (int*)(base + off); off += nBN * 4;
    float* amv = (float*)(base + off); off += nBN * 4;
    float* crvv = (float*)(base + off); off += nBN * 4;
    float* p_tss = (float*)(base + off); off += (size_t)nfb * 4;
    float* p_iou = (float*)(base + off); off += (size_t)nfb * 4;
    float* p_dfl = (float*)(base + off); off += (size_t)nfb * 4;
    float* p_cls = (float*)(base + off); off += (size_t)nfb * 4;
    off = (off + 7) & ~(size_t)7;  // align for u64
    unsigned long long* cand = (unsigned long long*)(base + off);
    size_t remain = (ws_size > off) ? (ws_size - off) : 0;
    int cap = (int)(remain / ((size_t)nbm * 8));
    if (cap > CAPMAX) cap = CAPMAX;
    if (cap < 1) cap = 1;

    dim3 grid(gx, Bv);
    hipMemsetAsync(cntv, 0, (size_t)nbm * 4, stream);
    k_cand<<<grid, 256, 0, stream>>>(cls, bdec, tgt, anc, cand, cntv,
                                     selmask, pos_al, pos_ov, Nv, cap);
    k_topk2<<<nbm, 256, 0, stream>>>(cand, cntv, selmask, Nv, cap);
    k_resolve<<<grid, 256, 0, stream>>>(cls, bdec, tgt, anc, selmask,
                                        gtfv, amv, crvv, pos_al, pos_ov, Nv);
    k_fused3<<<nfb, 256, 0, stream>>>(cls, bdist, tgt, anc, strd,
                                      gtfv, amv, crvv, pos_al, pos_ov,
                                      p_cls, p_tss, p_iou, p_dfl, nrows, Nv);
    k_final<<<1, 256, 0, stream>>>(p_cls, p_tss, p_iou, p_dfl, nfb,
                                   (float*)d_out, Bv);
}

// Round 18
// 120.866 us; speedup vs baseline: 1.5081x; 1.0007x over previous
//
#include <hip/hip_runtime.h>
#include <math.h>

#define MGT 32
#define NCLS 80
#define TEPS 1e-9f
#define CEPS 1e-7f
#define CAPMAX 4096

// hoisted-precompute CIoU: awh=w1*h1, aatan=atan(w1/(h1+eps)) for box a (gt),
// bwh/batan likewise for box b (pred). Bit-identical to the reference op order.
__device__ __forceinline__ float ciou_pre(float ax1, float ay1, float ax2, float ay2,
                                          float awh, float aatan,
                                          float bx1, float by1, float bx2, float by2,
                                          float bwh, float batan) {
    float iw = fmaxf(fminf(ax2, bx2) - fmaxf(ax1, bx1), 0.f);
    float ih = fmaxf(fminf(ay2, by2) - fmaxf(ay1, by1), 0.f);
    float inter = iw * ih;
    float uni = awh + bwh - inter + CEPS;
    float iou = inter / uni;
    float cw = fmaxf(ax2, bx2) - fminf(ax1, bx1);
    float ch = fmaxf(ay2, by2) - fminf(ay1, by1);
    float c2 = cw * cw + ch * ch + CEPS;
    float dx = bx1 + bx2 - ax1 - ax2;
    float dy = by1 + by2 - ay1 - ay2;
    float rho2 = (dx * dx + dy * dy) * 0.25f;
    float dv = batan - aatan;
    float v = 0.405284734569351f * dv * dv;  // 4/pi^2
    float alpha = v / (v - iou + (1.f + CEPS));
    return iou - (rho2 / c2 + v * alpha);
}

__device__ __forceinline__ float sigm_fast(float x) {
    return __builtin_amdgcn_rcpf(1.f + __expf(-x));
}

// ---- kernel: sparse align -> compact per-(b,m) candidate lists; zero-inits ----
// key = bits(al)<<32 | ~n : exact (max-val, min-idx) order; only al>0 appended.
__global__ __launch_bounds__(256) void k_cand(const float* __restrict__ cls,
                                              const float* __restrict__ bdec,
                                              const float* __restrict__ tgt,
                                              const float* __restrict__ anc,
                                              unsigned long long* __restrict__ cand,
                                              unsigned* __restrict__ cnt,
                                              unsigned* __restrict__ selmask,
                                              unsigned* __restrict__ pos_al,
                                              unsigned* __restrict__ pos_ov,
                                              int Nv, int cap) {
    __shared__ float sx1[MGT], sy1[MGT], sx2[MGT], sy2[MGT];
    __shared__ float swh[MGT], satan[MGT];
    __shared__ int slab[MGT], svld[MGT];
    int b = blockIdx.y, tid = threadIdx.x;
    if (tid < MGT) {
        const float* t = tgt + ((size_t)b * MGT + tid) * 5;
        float lf = t[0];
        float x1 = t[1], y1 = t[2], x2 = t[3], y2 = t[4];
        sx1[tid] = x1; sy1[tid] = y1; sx2[tid] = x2; sy2[tid] = y2;
        float gw = x2 - x1, gh = y2 - y1;
        swh[tid] = gw * gh;
        satan[tid] = atanf(gw / (gh + CEPS));
        float area = fmaxf(gw, 0.f) * fmaxf(gh, 0.f);
        int lab = (int)lf;
        svld[tid] = (lab >= 0 && area > 0.f) ? 1 : 0;
        slab[tid] = lab < 0 ? 0 : lab;
        if (blockIdx.x == 0) {  // zero pos maxes once per batch-row
            pos_al[b * MGT + tid] = 0u;
            pos_ov[b * MGT + tid] = 0u;
        }
    }
    __syncthreads();
    int n = blockIdx.x * 256 + tid;
    if (n >= Nv) return;
    size_t bn = (size_t)b * Nv + n;
    selmask[bn] = 0u;  // stream-ordered before k_topk2 ORs
    float4 p = reinterpret_cast<const float4*>(bdec)[bn];
    float2 a = reinterpret_cast<const float2*>(anc)[n];
    const float* crow = cls + bn * NCLS;
    float pw = p.z - p.x, ph = p.w - p.y;
    float pwh = pw * ph;
    float patan = 0.f; bool have_patan = false;
    int lane = tid & 63;
    for (int m = 0; m < MGT; ++m) {
        float al = 0.f;
        if (svld[m]) {
            float mn = fminf(fminf(a.x - sx1[m], a.y - sy1[m]),
                             fminf(sx2[m] - a.x, sy2[m] - a.y));
            if (mn > TEPS) {  // sparse: ~2% of pairs reach CIoU
                if (!have_patan) { patan = atanf(pw / (ph + CEPS)); have_patan = true; }
                float ov = fmaxf(ciou_pre(sx1[m], sy1[m], sx2[m], sy2[m],
                                          swh[m], satan[m],
                                          p.x, p.y, p.z, p.w, pwh, patan), 0.f);
                if (ov > 0.f) {
                    float s = sigm_fast(crow[slab[m]]);
                    float o2 = ov * ov;
                    al = __builtin_sqrtf(s) * o2 * o2 * o2;  // s^0.5 * ov^6
                }
            }
        }
        // wave-aggregated append (order within list is irrelevant: set semantics)
        unsigned long long msk = __ballot(al > 0.f);
        if (msk) {
            int leader = __ffsll((long long)msk) - 1;
            unsigned base = 0;
            if (lane == leader)
                base = atomicAdd(&cnt[b * MGT + m], (unsigned)__popcll(msk));
            base = __shfl(base, leader, 64);
            if (al > 0.f) {
                unsigned rank = (unsigned)__popcll(msk & ((1ull << lane) - 1ull));
                unsigned idx = base + rank;
                if ((int)idx < cap) {
                    unsigned long long key =
                        (((unsigned long long)__float_as_uint(al)) << 32) |
                        (unsigned)(0xFFFFFFFFu - (unsigned)n);
                    cand[((size_t)b * MGT + m) * cap + idx] = key;
                }
            }
        }
    }
}

// ---- kernel: per-(b,m) top-10 from compact list -> selmask (register queue) ----
__global__ __launch_bounds__(256) void k_topk2(const unsigned long long* __restrict__ cand,
                                               const unsigned* __restrict__ cnt,
                                               unsigned* __restrict__ selmask,
                                               int Nv, int cap) {
    __shared__ unsigned long long warp_r[4];
    __shared__ unsigned long long winner_s;
    int bid = blockIdx.x;          // = b*MGT + m
    int b = bid / MGT, m = bid - b * MGT;
    int tid = threadIdx.x;
    int total = (int)cnt[bid];
    if (total > cap) total = cap;
    const unsigned long long* row = cand + (size_t)bid * cap;
    unsigned long long v[10];  // ascending; v[9] = max
#pragma unroll
    for (int i = 0; i < 10; ++i) v[i] = 0ull;
    for (int i = tid; i < total; i += 256) {
        unsigned long long key = row[i];
        if (key > v[0]) {  // sorted ascending insert
            unsigned long long cv = key; bool placed = false;
#pragma unroll
            for (int j = 0; j < 9; ++j) {
                if (!placed) {
                    if (cv > v[j + 1]) { v[j] = v[j + 1]; }
                    else { v[j] = cv; placed = true; }
                }
            }
            if (!placed) v[9] = cv;
        }
    }
    for (int r = 0; r < 10; ++r) {
        unsigned long long cand_k = v[9];
        unsigned long long w = cand_k;
#pragma unroll
        for (int s = 32; s > 0; s >>= 1) {
            unsigned long long o = __shfl_xor(w, s, 64);
            w = (o > w) ? o : w;
        }
        if ((tid & 63) == 0) warp_r[tid >> 6] = w;
        __syncthreads();
        if (tid == 0) {
            unsigned long long ww = warp_r[0];
            ww = (warp_r[1] > ww) ? warp_r[1] : ww;
            ww = (warp_r[2] > ww) ? warp_r[2] : ww;
            ww = (warp_r[3] > ww) ? warp_r[3] : ww;
            winner_s = ww;
            float wv = __uint_as_float((unsigned)(ww >> 32));
            if (wv > TEPS) {
                unsigned wi = 0xFFFFFFFFu - (unsigned)(ww & 0xFFFFFFFFull);
                atomicOr(&selmask[(size_t)b * Nv + wi], 1u << m);
            }
        }
        __syncthreads();
        unsigned long long win = winner_s;
        if (win == 0ull) break;  // no more positive candidates
        if (cand_k == win) {     // unique owner (idx embedded): pop max, shift up
#pragma unroll
            for (int j = 9; j > 0; --j) v[j] = v[j - 1];
            v[0] = 0ull;
        }
        __syncthreads();
    }
}

// ---- kernel: resolve multi-assignment (lazy bestm), per-anchor gt/align/ciou ----
__global__ __launch_bounds__(256) void k_resolve(const float* __restrict__ cls,
                                                 const float* __restrict__ bdec,
                                                 const float* __restrict__ tgt,
                                                 const float* __restrict__ anc,
                                                 const unsigned* __restrict__ selmask,
                                                 int* __restrict__ gtf,
                                                 float* __restrict__ amv,
                                                 float* __restrict__ crv,
                                                 unsigned* __restrict__ pos_al,
                                                 unsigned* __restrict__ pos_ov, int Nv) {
    __shared__ float sx1[MGT], sy1[MGT], sx2[MGT], sy2[MGT];
    __shared__ float swh[MGT], satan[MGT];
    __shared__ int slab[MGT], svld[MGT];
    int b = blockIdx.y, tid = threadIdx.x;
    if (tid < MGT) {
        const float* t = tgt + ((size_t)b * MGT + tid) * 5;
        float lf = t[0];
        float x1 = t[1], y1 = t[2], x2 = t[3], y2 = t[4];
        sx1[tid] = x1; sy1[tid] = y1; sx2[tid] = x2; sy2[tid] = y2;
        float gw = x2 - x1, gh = y2 - y1;
        swh[tid] = gw * gh;
        satan[tid] = atanf(gw / (gh + CEPS));
        float area = fmaxf(gw, 0.f) * fmaxf(gh, 0.f);
        int lab = (int)lf;
        svld[tid] = (lab >= 0 && area > 0.f) ? 1 : 0;
        slab[tid] = lab < 0 ? 0 : lab;
    }
    __syncthreads();
    int n = blockIdx.x * 256 + tid;
    if (n >= Nv) return;
    size_t bn = (size_t)b * Nv + n;
    unsigned msk = selmask[bn];
    if (!msk) { gtf[bn] = -1; amv[bn] = 0.f; crv[bn] = 0.f; return; }
    float4 p = reinterpret_cast<const float4*>(bdec)[bn];
    float pw = p.z - p.x, ph = p.w - p.y;
    float pwh = pw * ph;
    float patan = atanf(pw / (ph + CEPS));
    int g;
    if (__popc(msk) > 1) {
        // lazy best = argmax_m clip(ciou,0), first-max tiebreak (unmasked)
        float bo = -1.f; g = 0;
        for (int m = 0; m < MGT; ++m) {
            float ov = fmaxf(ciou_pre(sx1[m], sy1[m], sx2[m], sy2[m],
                                      swh[m], satan[m],
                                      p.x, p.y, p.z, p.w, pwh, patan), 0.f);
            if (ov > bo) { bo = ov; g = m; }
        }
    } else {
        g = __ffs(msk) - 1;
    }
    float cr = ciou_pre(sx1[g], sy1[g], sx2[g], sy2[g], swh[g], satan[g],
                        p.x, p.y, p.z, p.w, pwh, patan);
    float ov = fmaxf(cr, 0.f);
    float al = 0.f;
    if (svld[g]) {
        float2 a = reinterpret_cast<const float2*>(anc)[n];
        float mn = fminf(fminf(a.x - sx1[g], a.y - sy1[g]),
                         fminf(sx2[g] - a.x, sy2[g] - a.y));
        if (mn > TEPS && ov > 0.f) {
            float s = sigm_fast(cls[bn * NCLS + slab[g]]);
            float o2 = ov * ov;
            al = __builtin_sqrtf(s) * o2 * o2 * o2;
        }
    }
    gtf[bn] = g; amv[bn] = al; crv[bn] = cr;
    atomicMax(&pos_al[b * MGT + g], __float_as_uint(al));
    atomicMax(&pos_ov[b * MGT + g], __float_as_uint(ov));
}

// ---- fused3: row-chunked two-phase (NO fence/done protocol);
//      phase1 per-row nv/tlab (+IoU/DFL), phase2 coalesced BCE sweep ----
__global__ __launch_bounds__(256) void k_fused3(const float* __restrict__ cls,
                                                const float* __restrict__ bdist,
                                                const float* __restrict__ tgt,
                                                const float* __restrict__ anc,
                                                const float* __restrict__ strd,
                                                const int* __restrict__ gtf,
                                                const float* __restrict__ amv,
                                                const float* __restrict__ crv,
                                                const unsigned* __restrict__ pos_al,
                                                const unsigned* __restrict__ pos_ov,
                                                float* __restrict__ p_cls,
                                                float* __restrict__ p_tss,
                                                float* __restrict__ p_iou,
                                                float* __restrict__ p_dfl,
                                                int nrows, int Nv) {
    __shared__ float s_nv[256];
    __shared__ int s_tl[256];
    __shared__ float r0[256], r1[256], r2[256], r3[256];
    int tid = threadIdx.x;
    int row0 = blockIdx.x * 256;
    int row = row0 + tid;
    float s_tss = 0.f, s_iou = 0.f, s_dfl = 0.f;
    // ---- phase 1: per-row nv/tlab once; rare IoU/DFL terms ----
    float nv = 0.f; int tl = -1;
    if (row < nrows) {
        int g = gtf[row];
        if (g >= 0) {
            int b = row / Nv;  // once per row
            float pa = __uint_as_float(pos_al[b * MGT + g]);
            float po = __uint_as_float(pos_ov[b * MGT + g]);
            nv = amv[row] * po / (pa + TEPS);
            const float* t5 = tgt + ((size_t)b * MGT + g) * 5;
            float lf = t5[0];
            tl = lf < 0.f ? 0 : (int)lf;
            if (nv > 0.f) {
                s_tss = nv;
                s_iou = (1.f - crv[row]) * nv;
                int n = row - b * Nv;
                float x1 = t5[1], y1 = t5[2], x2 = t5[3], y2 = t5[4];
                float2 a = reinterpret_cast<const float2*>(anc)[n];
                float st = strd[n];
                float ttv[4];
                ttv[0] = (a.x - x1) / st;
                ttv[1] = (a.y - y1) / st;
                ttv[2] = (x2 - a.x) / st;
                ttv[3] = (y2 - a.y) / st;
                const float* bd = bdist + (size_t)row * 64;
                float acc = 0.f;
#pragma unroll
                for (int k = 0; k < 4; ++k) {
                    float t = fminf(fmaxf(ttv[k], 0.f), 14.99f);
                    int tli = (int)t;
                    float wl = (float)(tli + 1) - t;
                    float mx = -3.4e38f;
                    for (int j = 0; j < 16; ++j) mx = fmaxf(mx, bd[k * 16 + j]);
                    float se = 0.f;
                    for (int j = 0; j < 16; ++j) se += __expf(bd[k * 16 + j] - mx);
                    float lse = mx + __logf(se);
                    float ll = bd[k * 16 + tli] - lse;
                    float lr = bd[k * 16 + tli + 1] - lse;
                    acc += ll * wl + lr * (1.f - wl);
                }
                s_dfl = (-acc * 0.25f) * nv;
            }
        }
    }
    s_nv[tid] = nv; s_tl[tid] = tl;
    __syncthreads();
    // ---- phase 2: coalesced sweep of this block's 256 rows x 20 float4 ----
    float s_cls = 0.f;
    int nrow_blk = nrows - row0;
    if (nrow_blk > 256) nrow_blk = 256;
    int tot = nrow_blk * 20;
    const float4* cbase = reinterpret_cast<const float4*>(cls) + (size_t)row0 * 20;
    for (int i = tid; i < tot; i += 256) {
        int r = i / 20;            // compile-time divisor: magic-mul
        int pos = i - r * 20;
        float4 x4 = cbase[i];
        float rnv = s_nv[r];
        int rtl = s_tl[r];
        int c0 = pos * 4;
        float xs[4] = {x4.x, x4.y, x4.z, x4.w};
#pragma unroll
        for (int e = 0; e < 4; ++e) {
            float x = xs[e];
            float ea = __expf(-fabsf(x));        // shared: sigmoid + log1p
            float rr = __builtin_amdgcn_rcpf(1.f + ea);
            float p = (x >= 0.f) ? rr : ea * rr; // sigmoid(x)
            float t = (c0 + e == rtl) ? rnv : 0.f;
            float bce = fmaxf(x, 0.f) - x * t + __logf(1.f + ea);
            float w = (t > 0.f) ? t : 0.75f * p * p;
            s_cls += bce * w;
        }
    }
    r0[tid] = s_cls; r1[tid] = s_tss; r2[tid] = s_iou; r3[tid] = s_dfl;
    __syncthreads();
    for (int s = 128; s > 0; s >>= 1) {
        if (tid < s) { r0[tid] += r0[tid + s]; r1[tid] += r1[tid + s];
                       r2[tid] += r2[tid + s]; r3[tid] += r3[tid + s]; }
        __syncthreads();
    }
    if (tid == 0) {
        int bid = blockIdx.x;
        p_cls[bid] = r0[0]; p_tss[bid] = r1[0];
        p_iou[bid] = r2[0]; p_dfl[bid] = r3[0];
    }
}

// ---- kernel: deterministic final reduce + combine (separate dispatch) ----
__global__ __launch_bounds__(256) void k_final(const float* __restrict__ p_cls,
                                               const float* __restrict__ p_tss,
                                               const float* __restrict__ p_iou,
                                               const float* __restrict__ p_dfl,
                                               int nbk, float* __restrict__ out, int Bv) {
    __shared__ float s0[256], s1[256], s2[256], s3[256];
    int tid = threadIdx.x;
    float a0 = 0.f, a1 = 0.f, a2 = 0.f, a3 = 0.f;
    for (int i = tid; i < nbk; i += 256) {
        a0 += p_cls[i]; a1 += p_tss[i]; a2 += p_iou[i]; a3 += p_dfl[i];
    }
    s0[tid] = a0; s1[tid] = a1; s2[tid] = a2; s3[tid] = a3;
    __syncthreads();
    for (int s = 128; s > 0; s >>= 1) {
        if (tid < s) { s0[tid] += s0[tid + s]; s1[tid] += s1[tid + s];
                       s2[tid] += s2[tid + s]; s3[tid] += s3[tid + s]; }
        __syncthreads();
    }
    if (tid == 0) {
        float tss = fmaxf(s1[0], 1.f);
        float lcls = 0.5f * s0[0] / tss;
        float liou = 7.5f * s2[0] / tss;
        float ldfl = 1.5f * s3[0] / tss;
        out[0] = (lcls + liou + ldfl) * (float)Bv;
        out[1] = lcls;
        out[2] = liou;
        out[3] = ldfl;
    }
}

extern "C" void kernel_launch(void* const* d_in, const int* in_sizes, int n_in,
                              void* d_out, int out_size, void* d_ws, size_t ws_size,
                              hipStream_t stream) {
    const float* cls = (const float*)d_in[0];
    const float* bdist = (const float*)d_in[1];
    const float* bdec = (const float*)d_in[2];
    const float* tgt = (const float*)d_in[3];
    const float* anc = (const float*)d_in[4];
    const float* strd = (const float*)d_in[5];
    int Nv = in_sizes[4] / 2;
    int Bv = in_sizes[3] / (MGT * 5);
    size_t nBN = (size_t)Bv * Nv;
    int gx = (Nv + 255) / 256;
    int nbm = Bv * MGT;
    int nrows = (int)nBN;
    int nfb = (nrows + 255) / 256;  // fused3 grid

    char* base = (char*)d_ws;
    size_t off = 0;
    unsigned* selmask = (unsigned*)(base + off); off += nBN * 4;
    unsigned* pos_al = (unsigned*)(base + off); off += (size_t)nbm * 4;
    unsigned* pos_ov = (unsigned*)(base + off); off += (size_t)nbm * 4;
    unsigned* cntv = (unsigned*)(base + off); off += (size_t)nbm * 4;
    int* gtfv = (int*)(base + off); off += nBN * 4;
    float* amv = (float*)(base + off); off += nBN * 4;
    float* crvv = (float*)(base + off); off += nBN * 4;
    float* p_tss = (float*)(base + off); off += (size_t)nfb * 4;
    float* p_iou = (float*)(base + off); off += (size_t)nfb * 4;
    float* p_dfl = (float*)(base + off); off += (size_t)nfb * 4;
    float* p_cls = (float*)(base + off); off += (size_t)nfb * 4;
    off = (off + 7) & ~(size_t)7;  // align for u64
    unsigned long long* cand = (unsigned long long*)(base + off);
    size_t remain = (ws_size > off) ? (ws_size - off) : 0;
    int cap = (int)(remain / ((size_t)nbm * 8));
    if (cap > CAPMAX) cap = CAPMAX;
    if (cap < 1) cap = 1;

    dim3 grid(gx, Bv);
    hipMemsetAsync(cntv, 0, (size_t)nbm * 4, stream);
    k_cand<<<grid, 256, 0, stream>>>(cls, bdec, tgt, anc, cand, cntv,
                                     selmask, pos_al, pos_ov, Nv, cap);
    k_topk2<<<nbm, 256, 0, stream>>>(cand, cntv, selmask, Nv, cap);
    k_resolve<<<grid, 256, 0, stream>>>(cls, bdec, tgt, anc, selmask,
                                        gtfv, amv, crvv, pos_al, pos_ov, Nv);
    k_fused3<<<nfb, 256, 0, stream>>>(cls, bdist, tgt, anc, strd,
                                      gtfv, amv, crvv, pos_al, pos_ov,
                                      p_cls, p_tss, p_iou, p_dfl, nrows, Nv);
    k_final<<<1, 256, 0, stream>>>(p_cls, p_tss, p_iou, p_dfl, nfb,
                                   (float*)d_out, Bv);
}

// Round 19
// 112.388 us; speedup vs baseline: 1.6219x; 1.0754x over previous
//
#include <hip/hip_runtime.h>
#include <math.h>

#define MGT 32
#define NCLS 80
#define TEPS 1e-9f
#define CEPS 1e-7f
#define CAPMAX 4096

// hoisted-precompute CIoU: awh=w1*h1, aatan=atan(w1/(h1+eps)) for box a (gt),
// bwh/batan likewise for box b (pred). Bit-identical to the reference op order.
__device__ __forceinline__ float ciou_pre(float ax1, float ay1, float ax2, float ay2,
                                          float awh, float aatan,
                                          float bx1, float by1, float bx2, float by2,
                                          float bwh, float batan) {
    float iw = fmaxf(fminf(ax2, bx2) - fmaxf(ax1, bx1), 0.f);
    float ih = fmaxf(fminf(ay2, by2) - fmaxf(ay1, by1), 0.f);
    float inter = iw * ih;
    float uni = awh + bwh - inter + CEPS;
    float iou = inter / uni;
    float cw = fmaxf(ax2, bx2) - fminf(ax1, bx1);
    float ch = fmaxf(ay2, by2) - fminf(ay1, by1);
    float c2 = cw * cw + ch * ch + CEPS;
    float dx = bx1 + bx2 - ax1 - ax2;
    float dy = by1 + by2 - ay1 - ay2;
    float rho2 = (dx * dx + dy * dy) * 0.25f;
    float dv = batan - aatan;
    float v = 0.405284734569351f * dv * dv;  // 4/pi^2
    float alpha = v / (v - iou + (1.f + CEPS));
    return iou - (rho2 / c2 + v * alpha);
}

__device__ __forceinline__ float sigm_fast(float x) {
    return __builtin_amdgcn_rcpf(1.f + __expf(-x));
}

// ---- kernel: sparse align -> compact per-(b,m) candidate lists; zero-inits ----
// key = bits(al)<<32 | ~n : exact (max-val, min-idx) order; only al>0 appended.
__global__ __launch_bounds__(256) void k_cand(const float* __restrict__ cls,
                                              const float* __restrict__ bdec,
                                              const float* __restrict__ tgt,
                                              const float* __restrict__ anc,
                                              unsigned long long* __restrict__ cand,
                                              unsigned* __restrict__ cnt,
                                              unsigned* __restrict__ selmask,
                                              unsigned* __restrict__ pos_al,
                                              unsigned* __restrict__ pos_ov,
                                              int Nv, int cap) {
    __shared__ float sx1[MGT], sy1[MGT], sx2[MGT], sy2[MGT];
    __shared__ float swh[MGT], satan[MGT];
    __shared__ int slab[MGT], svld[MGT];
    int b = blockIdx.y, tid = threadIdx.x;
    if (tid < MGT) {
        const float* t = tgt + ((size_t)b * MGT + tid) * 5;
        float lf = t[0];
        float x1 = t[1], y1 = t[2], x2 = t[3], y2 = t[4];
        sx1[tid] = x1; sy1[tid] = y1; sx2[tid] = x2; sy2[tid] = y2;
        float gw = x2 - x1, gh = y2 - y1;
        swh[tid] = gw * gh;
        satan[tid] = atanf(gw / (gh + CEPS));
        float area = fmaxf(gw, 0.f) * fmaxf(gh, 0.f);
        int lab = (int)lf;
        svld[tid] = (lab >= 0 && area > 0.f) ? 1 : 0;
        slab[tid] = lab < 0 ? 0 : lab;
        if (blockIdx.x == 0) {  // zero pos maxes once per batch-row
            pos_al[b * MGT + tid] = 0u;
            pos_ov[b * MGT + tid] = 0u;
        }
    }
    __syncthreads();
    int n = blockIdx.x * 256 + tid;
    if (n >= Nv) return;
    size_t bn = (size_t)b * Nv + n;
    selmask[bn] = 0u;  // stream-ordered before k_topk2 ORs
    float4 p = reinterpret_cast<const float4*>(bdec)[bn];
    float2 a = reinterpret_cast<const float2*>(anc)[n];
    const float* crow = cls + bn * NCLS;
    float pw = p.z - p.x, ph = p.w - p.y;
    float pwh = pw * ph;
    float patan = 0.f; bool have_patan = false;
    int lane = tid & 63;
    for (int m = 0; m < MGT; ++m) {
        float al = 0.f;
        if (svld[m]) {
            float mn = fminf(fminf(a.x - sx1[m], a.y - sy1[m]),
                             fminf(sx2[m] - a.x, sy2[m] - a.y));
            if (mn > TEPS) {  // sparse: ~2% of pairs reach CIoU
                if (!have_patan) { patan = atanf(pw / (ph + CEPS)); have_patan = true; }
                float ov = fmaxf(ciou_pre(sx1[m], sy1[m], sx2[m], sy2[m],
                                          swh[m], satan[m],
                                          p.x, p.y, p.z, p.w, pwh, patan), 0.f);
                if (ov > 0.f) {
                    float s = sigm_fast(crow[slab[m]]);
                    float o2 = ov * ov;
                    al = __builtin_sqrtf(s) * o2 * o2 * o2;  // s^0.5 * ov^6
                }
            }
        }
        // wave-aggregated append (order within list is irrelevant: set semantics)
        unsigned long long msk = __ballot(al > 0.f);
        if (msk) {
            int leader = __ffsll((long long)msk) - 1;
            unsigned base = 0;
            if (lane == leader)
                base = atomicAdd(&cnt[b * MGT + m], (unsigned)__popcll(msk));
            base = __shfl(base, leader, 64);
            if (al > 0.f) {
                unsigned rank = (unsigned)__popcll(msk & ((1ull << lane) - 1ull));
                unsigned idx = base + rank;
                if ((int)idx < cap) {
                    unsigned long long key =
                        (((unsigned long long)__float_as_uint(al)) << 32) |
                        (unsigned)(0xFFFFFFFFu - (unsigned)n);
                    cand[((size_t)b * MGT + m) * cap + idx] = key;
                }
            }
        }
    }
}

// ---- kernel: per-(b,m) top-10 from compact list -> selmask + winner list ----
__global__ __launch_bounds__(256) void k_topk2(const unsigned long long* __restrict__ cand,
                                               const unsigned* __restrict__ cnt,
                                               unsigned* __restrict__ selmask,
                                               int* __restrict__ wlist,
                                               int Nv, int cap) {
    __shared__ unsigned long long warp_r[4];
    __shared__ unsigned long long winner_s;
    int bid = blockIdx.x;          // = b*MGT + m
    int b = bid / MGT, m = bid - b * MGT;
    int tid = threadIdx.x;
    if (tid < 10) wlist[bid * 10 + tid] = -1;  // default: no winner
    int total = (int)cnt[bid];
    if (total > cap) total = cap;
    const unsigned long long* row = cand + (size_t)bid * cap;
    unsigned long long v[10];  // ascending; v[9] = max
#pragma unroll
    for (int i = 0; i < 10; ++i) v[i] = 0ull;
    for (int i = tid; i < total; i += 256) {
        unsigned long long key = row[i];
        if (key > v[0]) {  // sorted ascending insert
            unsigned long long cv = key; bool placed = false;
#pragma unroll
            for (int j = 0; j < 9; ++j) {
                if (!placed) {
                    if (cv > v[j + 1]) { v[j] = v[j + 1]; }
                    else { v[j] = cv; placed = true; }
                }
            }
            if (!placed) v[9] = cv;
        }
    }
    __syncthreads();  // wlist defaults visible before overwrites
    for (int r = 0; r < 10; ++r) {
        unsigned long long cand_k = v[9];
        unsigned long long w = cand_k;
#pragma unroll
        for (int s = 32; s > 0; s >>= 1) {
            unsigned long long o = __shfl_xor(w, s, 64);
            w = (o > w) ? o : w;
        }
        if ((tid & 63) == 0) warp_r[tid >> 6] = w;
        __syncthreads();
        if (tid == 0) {
            unsigned long long ww = warp_r[0];
            ww = (warp_r[1] > ww) ? warp_r[1] : ww;
            ww = (warp_r[2] > ww) ? warp_r[2] : ww;
            ww = (warp_r[3] > ww) ? warp_r[3] : ww;
            winner_s = ww;
            float wv = __uint_as_float((unsigned)(ww >> 32));
            if (wv > TEPS) {
                unsigned wi = 0xFFFFFFFFu - (unsigned)(ww & 0xFFFFFFFFull);
                atomicOr(&selmask[(size_t)b * Nv + wi], 1u << m);
                wlist[bid * 10 + r] = (int)wi;
            }
        }
        __syncthreads();
        unsigned long long win = winner_s;
        if (win == 0ull) break;  // no more positive candidates
        if (cand_k == win) {     // unique owner (idx embedded): pop max, shift up
#pragma unroll
            for (int j = 9; j > 0; --j) v[j] = v[j - 1];
            v[0] = 0ull;
        }
        __syncthreads();
    }
}

// ---- kernel: resolve winners only (<=10 per (b,m) block); duplicates across
//      blocks compute byte-identical values -> benign, deterministic ----
__global__ __launch_bounds__(64) void k_resolve2(const float* __restrict__ cls,
                                                 const float* __restrict__ bdec,
                                                 const float* __restrict__ tgt,
                                                 const float* __restrict__ anc,
                                                 const unsigned* __restrict__ selmask,
                                                 const int* __restrict__ wlist,
                                                 int* __restrict__ gtf,
                                                 float* __restrict__ amv,
                                                 float* __restrict__ crv,
                                                 unsigned* __restrict__ pos_al,
                                                 unsigned* __restrict__ pos_ov, int Nv) {
    __shared__ float sx1[MGT], sy1[MGT], sx2[MGT], sy2[MGT];
    __shared__ float swh[MGT], satan[MGT];
    __shared__ int slab[MGT], svld[MGT];
    int bid = blockIdx.x;          // = b*MGT + m
    int b = bid / MGT;
    int tid = threadIdx.x;
    if (tid < MGT) {
        const float* t = tgt + ((size_t)b * MGT + tid) * 5;
        float lf = t[0];
        float x1 = t[1], y1 = t[2], x2 = t[3], y2 = t[4];
        sx1[tid] = x1; sy1[tid] = y1; sx2[tid] = x2; sy2[tid] = y2;
        float gw = x2 - x1, gh = y2 - y1;
        swh[tid] = gw * gh;
        satan[tid] = atanf(gw / (gh + CEPS));
        float area = fmaxf(gw, 0.f) * fmaxf(gh, 0.f);
        int lab = (int)lf;
        svld[tid] = (lab >= 0 && area > 0.f) ? 1 : 0;
        slab[tid] = lab < 0 ? 0 : lab;
    }
    __syncthreads();
    if (tid >= 10) return;
    int n = wlist[bid * 10 + tid];
    if (n < 0) return;
    size_t bn = (size_t)b * Nv + n;
    unsigned msk = selmask[bn];  // complete (stream-ordered after k_topk2)
    float4 p = reinterpret_cast<const float4*>(bdec)[bn];
    float pw = p.z - p.x, ph = p.w - p.y;
    float pwh = pw * ph;
    float patan = atanf(pw / (ph + CEPS));
    int g;
    if (__popc(msk) > 1) {
        // lazy best = argmax_m clip(ciou,0), first-max tiebreak (unmasked)
        float bo = -1.f; g = 0;
        for (int m = 0; m < MGT; ++m) {
            float ov = fmaxf(ciou_pre(sx1[m], sy1[m], sx2[m], sy2[m],
                                      swh[m], satan[m],
                                      p.x, p.y, p.z, p.w, pwh, patan), 0.f);
            if (ov > bo) { bo = ov; g = m; }
        }
    } else {
        g = __ffs(msk) - 1;
    }
    float cr = ciou_pre(sx1[g], sy1[g], sx2[g], sy2[g], swh[g], satan[g],
                        p.x, p.y, p.z, p.w, pwh, patan);
    float ov = fmaxf(cr, 0.f);
    float al = 0.f;
    if (svld[g]) {
        float2 a = reinterpret_cast<const float2*>(anc)[n];
        float mn = fminf(fminf(a.x - sx1[g], a.y - sy1[g]),
                         fminf(sx2[g] - a.x, sy2[g] - a.y));
        if (mn > TEPS && ov > 0.f) {
            float s = sigm_fast(cls[bn * NCLS + slab[g]]);
            float o2 = ov * ov;
            al = __builtin_sqrtf(s) * o2 * o2 * o2;
        }
    }
    gtf[bn] = g; amv[bn] = al; crv[bn] = cr;  // duplicates write same values
    atomicMax(&pos_al[b * MGT + g], __float_as_uint(al));
    atomicMax(&pos_ov[b * MGT + g], __float_as_uint(ov));
}

// ---- fused3: row-chunked two-phase; selmask-gated (gtf only valid if fg) ----
__global__ __launch_bounds__(256) void k_fused3(const float* __restrict__ cls,
                                                const float* __restrict__ bdist,
                                                const float* __restrict__ tgt,
                                                const float* __restrict__ anc,
                                                const float* __restrict__ strd,
                                                const unsigned* __restrict__ selmask,
                                                const int* __restrict__ gtf,
                                                const float* __restrict__ amv,
                                                const float* __restrict__ crv,
                                                const unsigned* __restrict__ pos_al,
                                                const unsigned* __restrict__ pos_ov,
                                                float* __restrict__ p_cls,
                                                float* __restrict__ p_tss,
                                                float* __restrict__ p_iou,
                                                float* __restrict__ p_dfl,
                                                int nrows, int Nv) {
    __shared__ float s_nv[256];
    __shared__ int s_tl[256];
    __shared__ float r0[256], r1[256], r2[256], r3[256];
    int tid = threadIdx.x;
    int row0 = blockIdx.x * 256;
    int row = row0 + tid;
    float s_tss = 0.f, s_iou = 0.f, s_dfl = 0.f;
    // ---- phase 1: per-row nv/tlab once; rare IoU/DFL terms ----
    float nv = 0.f; int tl = -1;
    if (row < nrows && selmask[row] != 0u) {
        int g = gtf[row];  // written by k_resolve2 for every selected anchor
        int b = row / Nv;  // once per row
        float pa = __uint_as_float(pos_al[b * MGT + g]);
        float po = __uint_as_float(pos_ov[b * MGT + g]);
        nv = amv[row] * po / (pa + TEPS);
        const float* t5 = tgt + ((size_t)b * MGT + g) * 5;
        float lf = t5[0];
        tl = lf < 0.f ? 0 : (int)lf;
        if (nv > 0.f) {
            s_tss = nv;
            s_iou = (1.f - crv[row]) * nv;
            int n = row - b * Nv;
            float x1 = t5[1], y1 = t5[2], x2 = t5[3], y2 = t5[4];
            float2 a = reinterpret_cast<const float2*>(anc)[n];
            float st = strd[n];
            float ttv[4];
            ttv[0] = (a.x - x1) / st;
            ttv[1] = (a.y - y1) / st;
            ttv[2] = (x2 - a.x) / st;
            ttv[3] = (y2 - a.y) / st;
            const float* bd = bdist + (size_t)row * 64;
            float acc = 0.f;
#pragma unroll
            for (int k = 0; k < 4; ++k) {
                float t = fminf(fmaxf(ttv[k], 0.f), 14.99f);
                int tli = (int)t;
                float wl = (float)(tli + 1) - t;
                float mx = -3.4e38f;
                for (int j = 0; j < 16; ++j) mx = fmaxf(mx, bd[k * 16 + j]);
                float se = 0.f;
                for (int j = 0; j < 16; ++j) se += __expf(bd[k * 16 + j] - mx);
                float lse = mx + __logf(se);
                float ll = bd[k * 16 + tli] - lse;
                float lr = bd[k * 16 + tli + 1] - lse;
                acc += ll * wl + lr * (1.f - wl);
            }
            s_dfl = (-acc * 0.25f) * nv;
        }
    }
    s_nv[tid] = nv; s_tl[tid] = tl;
    __syncthreads();
    // ---- phase 2: coalesced sweep of this block's 256 rows x 20 float4 ----
    float s_cls = 0.f;
    int nrow_blk = nrows - row0;
    if (nrow_blk > 256) nrow_blk = 256;
    int tot = nrow_blk * 20;
    const float4* cbase = reinterpret_cast<const float4*>(cls) + (size_t)row0 * 20;
    for (int i = tid; i < tot; i += 256) {
        int r = i / 20;            // compile-time divisor: magic-mul
        int pos = i - r * 20;
        float4 x4 = cbase[i];
        float rnv = s_nv[r];
        int rtl = s_tl[r];
        int c0 = pos * 4;
        float xs[4] = {x4.x, x4.y, x4.z, x4.w};
#pragma unroll
        for (int e = 0; e < 4; ++e) {
            float x = xs[e];
            float ea = __expf(-fabsf(x));        // shared: sigmoid + log1p
            float rr = __builtin_amdgcn_rcpf(1.f + ea);
            float p = (x >= 0.f) ? rr : ea * rr; // sigmoid(x)
            float t = (c0 + e == rtl) ? rnv : 0.f;
            float bce = fmaxf(x, 0.f) - x * t + __logf(1.f + ea);
            float w = (t > 0.f) ? t : 0.75f * p * p;
            s_cls += bce * w;
        }
    }
    r0[tid] = s_cls; r1[tid] = s_tss; r2[tid] = s_iou; r3[tid] = s_dfl;
    __syncthreads();
    for (int s = 128; s > 0; s >>= 1) {
        if (tid < s) { r0[tid] += r0[tid + s]; r1[tid] += r1[tid + s];
                       r2[tid] += r2[tid + s]; r3[tid] += r3[tid + s]; }
        __syncthreads();
    }
    if (tid == 0) {
        int bid = blockIdx.x;
        p_cls[bid] = r0[0]; p_tss[bid] = r1[0];
        p_iou[bid] = r2[0]; p_dfl[bid] = r3[0];
    }
}

// ---- kernel: deterministic final reduce + combine (separate dispatch) ----
__global__ __launch_bounds__(256) void k_final(const float* __restrict__ p_cls,
                                               const float* __restrict__ p_tss,
                                               const float* __restrict__ p_iou,
                                               const float* __restrict__ p_dfl,
                                               int nbk, float* __restrict__ out, int Bv) {
    __shared__ float s0[256], s1[256], s2[256], s3[256];
    int tid = threadIdx.x;
    float a0 = 0.f, a1 = 0.f, a2 = 0.f, a3 = 0.f;
    for (int i = tid; i < nbk; i += 256) {
        a0 += p_cls[i]; a1 += p_tss[i]; a2 += p_iou[i]; a3 += p_dfl[i];
    }
    s0[tid] = a0; s1[tid] = a1; s2[tid] = a2; s3[tid] = a3;
    __syncthreads();
    for (int s = 128; s > 0; s >>= 1) {
        if (tid < s) { s0[tid] += s0[tid + s]; s1[tid] += s1[tid + s];
                       s2[tid] += s2[tid + s]; s3[tid] += s3[tid + s]; }
        __syncthreads();
    }
    if (tid == 0) {
        float tss = fmaxf(s1[0], 1.f);
        float lcls = 0.5f * s0[0] / tss;
        float liou = 7.5f * s2[0] / tss;
        float ldfl = 1.5f * s3[0] / tss;
        out[0] = (lcls + liou + ldfl) * (float)Bv;
        out[1] = lcls;
        out[2] = liou;
        out[3] = ldfl;
    }
}

extern "C" void kernel_launch(void* const* d_in, const int* in_sizes, int n_in,
                              void* d_out, int out_size, void* d_ws, size_t ws_size,
                              hipStream_t stream) {
    const float* cls = (const float*)d_in[0];
    const float* bdist = (const float*)d_in[1];
    const float* bdec = (const float*)d_in[2];
    const float* tgt = (const float*)d_in[3];
    const float* anc = (const float*)d_in[4];
    const float* strd = (const float*)d_in[5];
    int Nv = in_sizes[4] / 2;
    int Bv = in_sizes[3] / (MGT * 5);
    size_t nBN = (size_t)Bv * Nv;
    int gx = (Nv + 255) / 256;
    int nbm = Bv * MGT;
    int nrows = (int)nBN;
    int nfb = (nrows + 255) / 256;  // fused3 grid

    char* base = (char*)d_ws;
    size_t off = 0;
    unsigned* selmask = (unsigned*)(base + off); off += nBN * 4;
    unsigned* pos_al = (unsigned*)(base + off); off += (size_t)nbm * 4;
    unsigned* pos_ov = (unsigned*)(base + off); off += (size_t)nbm * 4;
    unsigned* cntv = (unsigned*)(base + off); off += (size_t)nbm * 4;
    int* wlist = (int*)(base + off); off += (size_t)nbm * 10 * 4;
    int* gtfv = (int*)(base + off); off += nBN * 4;
    float* amv = (float*)(base + off); off += nBN * 4;
    float* crvv = (float*)(base + off); off += nBN * 4;
    float* p_tss = (float*)(base + off); off += (size_t)nfb * 4;
    float* p_iou = (float*)(base + off); off += (size_t)nfb * 4;
    float* p_dfl = (float*)(base + off); off += (size_t)nfb * 4;
    float* p_cls = (float*)(base + off); off += (size_t)nfb * 4;
    off = (off + 7) & ~(size_t)7;  // align for u64
    unsigned long long* cand = (unsigned long long*)(base + off);
    size_t remain = (ws_size > off) ? (ws_size - off) : 0;
    int cap = (int)(remain / ((size_t)nbm * 8));
    if (cap > CAPMAX) cap = CAPMAX;
    if (cap < 1) cap = 1;

    dim3 grid(gx, Bv);
    hipMemsetAsync(cntv, 0, (size_t)nbm * 4, stream);
    k_cand<<<grid, 256, 0, stream>>>(cls, bdec, tgt, anc, cand, cntv,
                                     selmask, pos_al, pos_ov, Nv, cap);
    k_topk2<<<nbm, 256, 0, stream>>>(cand, cntv, selmask, wlist, Nv, cap);
    k_resolve2<<<nbm, 64, 0, stream>>>(cls, bdec, tgt, anc, selmask, wlist,
                                       gtfv, amv, crvv, pos_al, pos_ov, Nv);
    k_fused3<<<nfb, 256, 0, stream>>>(cls, bdist, tgt, anc, strd, selmask,
                                      gtfv, amv, crvv, pos_al, pos_ov,
                                      p_cls, p_tss, p_iou, p_dfl, nrows, Nv);
    k_final<<<1, 256, 0, stream>>>(p_cls, p_tss, p_iou, p_dfl, nfb,
                                   (float*)d_out, Bv);
}